// Round 8
// baseline (16575.844 us; speedup 1.0000x reference)
//
#include <hip/hip_runtime.h>
#include <hip/hip_bf16.h>

#define NN 100000
#define NE 1600000
#define DD 64
#define NG 512
#define POOLED_F (NG * 3 * DD)   // 98304
#define STATS_F  (3 * 128)

__global__ __launch_bounds__(256) void k_zero(float* __restrict__ p, int n) {
    int i = blockIdx.x * 256 + threadIdx.x;
    if (i < n) p[i] = 0.f;
}

__global__ __launch_bounds__(256) void k_sentinel(float* out, float val) {
    if (threadIdx.x == 0 && blockIdx.x == 0) out[0] = val;
}

// agg <- h  (float4 copy)
__global__ __launch_bounds__(256) void k_copy(const float* __restrict__ src,
                                              float* __restrict__ agg) {
    int total = NN * DD / 4;
    for (int i = blockIdx.x * 256 + threadIdx.x; i < total; i += gridDim.x * 256)
        ((float4*)agg)[i] = ((const float4*)src)[i];
}

// ---------------- edge: msg = relu(h[src] + ea@W + b); atomicAdd into agg[dst]
// (agg pre-loaded with h, so agg ends as z = h + sum(msg))
__global__ __launch_bounds__(256) void k_edge(
    const float* __restrict__ ea, const float* __restrict__ h,
    const float* __restrict__ W, const float* __restrict__ bias,
    const int* __restrict__ src, const int* __restrict__ dst,
    float* __restrict__ agg)
{
    __shared__ __align__(16) float Wl[DD * DD];
    __shared__ __align__(16) float bl[DD];
    int tid = threadIdx.x;
    for (int i = tid; i < DD * DD / 4; i += 256)
        ((float4*)Wl)[i] = ((const float4*)W)[i];
    if (tid < DD / 4) ((float4*)bl)[tid] = ((const float4*)bias)[tid];
    __syncthreads();

    int e = blockIdx.x * 256 + tid;          // NE % 256 == 0
    int s = src[e], d = dst[e];

    float av[DD];
    const float4* earow = (const float4*)(ea + (size_t)e * DD);
#pragma unroll
    for (int i = 0; i < DD / 4; ++i) {
        float4 t = earow[i];
        av[4*i] = t.x; av[4*i+1] = t.y; av[4*i+2] = t.z; av[4*i+3] = t.w;
    }
    const float4* hrow = (const float4*)(h + (size_t)s * DD);
    float* arow = agg + (size_t)d * DD;

    for (int c4 = 0; c4 < DD / 4; ++c4) {
        float4 acc = ((float4*)bl)[c4];
#pragma unroll
        for (int k = 0; k < DD; ++k) {
            float4 w = ((float4*)Wl)[k * (DD/4) + c4];   // wave-uniform broadcast
            acc.x = fmaf(av[k], w.x, acc.x);
            acc.y = fmaf(av[k], w.y, acc.y);
            acc.z = fmaf(av[k], w.z, acc.z);
            acc.w = fmaf(av[k], w.w, acc.w);
        }
        float4 hv = hrow[c4];
        atomicAdd(arow + c4*4 + 0, fmaxf(hv.x + acc.x, 0.f));
        atomicAdd(arow + c4*4 + 1, fmaxf(hv.y + acc.y, 0.f));
        atomicAdd(arow + c4*4 + 2, fmaxf(hv.z + acc.z, 0.f));
        atomicAdd(arow + c4*4 + 3, fmaxf(hv.w + acc.w, 0.f));
    }
}

// ---------------- node GEMV + relu, in-place safe (row in regs before store)
__global__ __launch_bounds__(256) void k_gemv_relu(
    const float* in, const float* __restrict__ W,
    const float* __restrict__ bias, float* out)
{
    __shared__ __align__(16) float Wl[DD * DD];
    __shared__ __align__(16) float bl[DD];
    int tid = threadIdx.x;
    for (int i = tid; i < DD * DD / 4; i += 256)
        ((float4*)Wl)[i] = ((const float4*)W)[i];
    if (tid < DD / 4) ((float4*)bl)[tid] = ((const float4*)bias)[tid];
    __syncthreads();

    int n = blockIdx.x * 256 + tid;
    if (n >= NN) return;

    float xr[DD];
    const float4* inrow = (const float4*)(in + (size_t)n * DD);
#pragma unroll
    for (int i = 0; i < DD / 4; ++i) {
        float4 t = inrow[i];
        xr[4*i] = t.x; xr[4*i+1] = t.y; xr[4*i+2] = t.z; xr[4*i+3] = t.w;
    }
    float4* outrow = (float4*)(out + (size_t)n * DD);
    for (int c4 = 0; c4 < DD / 4; ++c4) {
        float4 acc = ((float4*)bl)[c4];
#pragma unroll
        for (int k = 0; k < DD; ++k) {
            float4 w = ((float4*)Wl)[k * (DD/4) + c4];
            acc.x = fmaf(xr[k], w.x, acc.x);
            acc.y = fmaf(xr[k], w.y, acc.y);
            acc.z = fmaf(xr[k], w.z, acc.z);
            acc.w = fmaf(xr[k], w.w, acc.w);
        }
        float4 o;
        o.x = fmaxf(acc.x, 0.f); o.y = fmaxf(acc.y, 0.f);
        o.z = fmaxf(acc.z, 0.f); o.w = fmaxf(acc.w, 0.f);
        outrow[c4] = o;
    }
}

// ---------------- BN stats (sum, sumsq) — coalesced, block-partial + atomics
__global__ __launch_bounds__(256) void k_stats(const float* __restrict__ z,
                                               float* __restrict__ stats) {
    int tid = threadIdx.x;
    int c = tid & 63;
    float s = 0.f, s2 = 0.f;
    for (int n = blockIdx.x * 4 + (tid >> 6); n < NN; n += 1024) {
        float v = z[(size_t)n * DD + c];
        s += v;
        s2 = fmaf(v, v, s2);
    }
    __shared__ float red[512];
    red[tid] = s; red[256 + tid] = s2;
    __syncthreads();
    if (tid < 64) {
        float a = red[tid] + red[64+tid] + red[128+tid] + red[192+tid];
        float b = red[256+tid] + red[320+tid] + red[384+tid] + red[448+tid];
        atomicAdd(&stats[c], a);
        atomicAdd(&stats[64 + c], b);
    }
}

__global__ void k_bnfinal(float* __restrict__ stats,
                          const float* __restrict__ gamma,
                          const float* __restrict__ beta) {
    int c = threadIdx.x;  // 64 threads
    float mu  = stats[c] * (1.0f / NN);
    float var = stats[64 + c] * (1.0f / NN) - mu * mu;
    float rstd = rsqrtf(var + 1e-5f);
    float sc = gamma[c] * rstd;
    stats[c] = sc;
    stats[64 + c] = beta[c] - sc * mu;
}

// ---------------- normalize -> f32 h (d_out region) + pooled atomics (d_out)
__global__ __launch_bounds__(256) void k_norm_pool(
    const float* __restrict__ z, const float* __restrict__ stats,
    const int* __restrict__ batch, float* __restrict__ hout,
    float* __restrict__ pooled, int l)
{
    int total = NN * DD / 4;
    for (int i = blockIdx.x * 256 + threadIdx.x; i < total; i += gridDim.x * 256) {
        int n  = i >> 4;
        int c4 = i & 15;
        float4 v  = ((const float4*)z)[i];
        float4 sc = ((const float4*)stats)[c4];
        float4 sh = ((const float4*)stats)[16 + c4];
        float4 o;
        o.x = fmaf(v.x, sc.x, sh.x);
        o.y = fmaf(v.y, sc.y, sh.y);
        o.z = fmaf(v.z, sc.z, sh.z);
        o.w = fmaf(v.w, sc.w, sh.w);
        ((float4*)hout)[i] = o;
        int g = batch[n];
        float* pp = pooled + (size_t)g * (3 * DD) + l * DD + c4 * 4;
        atomicAdd(pp + 0, o.x);
        atomicAdd(pp + 1, o.y);
        atomicAdd(pp + 2, o.z);
        atomicAdd(pp + 3, o.w);
    }
}

// ----------------------------------------------------------------------------
extern "C" void kernel_launch(void* const* d_in, const int* in_sizes, int n_in,
                              void* d_out, int out_size, void* d_ws, size_t ws_size,
                              hipStream_t stream) {
    const float* x     = (const float*)d_in[0];
    const float* ea    = (const float*)d_in[1];
    const float* We    = (const float*)d_in[2];
    const float* be    = (const float*)d_in[3];
    const float* W1    = (const float*)d_in[4];
    const float* b1    = (const float*)d_in[5];
    const float* W2    = (const float*)d_in[6];
    const float* b2    = (const float*)d_in[7];
    const float* gamma = (const float*)d_in[8];
    const float* beta  = (const float*)d_in[9];
    const int*   eidx  = (const int*)d_in[10];
    const int*   batch = (const int*)d_in[11];
    const int* src = eidx;            // reference: src = edge_index[0]
    const int* dst = eidx + NE;       //            dst = edge_index[1]

    float* out_pool = (float*)d_out;                  // [NG, 3*DD] f32
    float* out_h    = out_pool + POOLED_F;            // [NN, DD]  f32

    float* agg   = (float*)d_ws;                      // NN*DD f32
    float* stats = agg + (size_t)NN * DD;             // STATS_F f32

    const int exp_sizes[12] = {6400000, 102400000, 12288, 192, 12288, 192,
                               12288, 192, 192, 192, 3200000, 100000};
    bool ok = (n_in == 12);
    for (int i = 0; ok && i < 12; ++i) ok = (in_sizes[i] == exp_sizes[i]);
    if (!ok) {
        k_sentinel<<<1, 64, 0, stream>>>((float*)d_out, 16384.0f);
        return;
    }
    if (ws_size < ((size_t)NN * DD + STATS_F) * sizeof(float)) {
        k_sentinel<<<1, 64, 0, stream>>>((float*)d_out, 32768.0f);
        return;
    }

    // zero pooled (in d_out) and stats each call — replay-deterministic
    k_zero<<<(POOLED_F + 255) / 256, 256, 0, stream>>>(out_pool, POOLED_F);
    k_zero<<<(STATS_F + 255) / 256, 256, 0, stream>>>(stats, STATS_F);

    for (int l = 0; l < 3; ++l) {
        const float* h = (l == 0) ? x : out_h;
        k_copy<<<2048, 256, 0, stream>>>(h, agg);   // agg <- h (z = h + sum m)
        k_edge<<<NE / 256, 256, 0, stream>>>(ea, h, We + l * DD * DD, be + l * DD,
                                             src, dst, agg);
        k_gemv_relu<<<(NN + 255) / 256, 256, 0, stream>>>(agg, W1 + l * DD * DD,
                                                          b1 + l * DD, agg);
        k_gemv_relu<<<(NN + 255) / 256, 256, 0, stream>>>(agg, W2 + l * DD * DD,
                                                          b2 + l * DD, agg);
        k_stats<<<256, 256, 0, stream>>>(agg, stats + l * 128);
        k_bnfinal<<<1, 64, 0, stream>>>(stats + l * 128, gamma + l * DD, beta + l * DD);
        k_norm_pool<<<2048, 256, 0, stream>>>(agg, stats + l * 128, batch,
                                              out_h, out_pool, l);
    }
}

// Round 9
// 3325.412 us; speedup vs baseline: 4.9846x; 4.9846x over previous
//
#include <hip/hip_runtime.h>
#include <hip/hip_bf16.h>

#define NN 100000
#define NE 1600000
#define DD 64
#define NG 512
#define POOLED_F (NG * 3 * DD)   // 98304
#define STATS_F  (3 * 128)

__global__ __launch_bounds__(256) void k_zero(float* __restrict__ p, int n) {
    int i = blockIdx.x * 256 + threadIdx.x;
    if (i < n) p[i] = 0.f;
}
__global__ __launch_bounds__(256) void k_zeroi(int* __restrict__ p, int n) {
    int i = blockIdx.x * 256 + threadIdx.x;
    if (i < n) p[i] = 0;
}
__global__ __launch_bounds__(256) void k_sentinel(float* out, float val) {
    if (threadIdx.x == 0 && blockIdx.x == 0) out[0] = val;
}

// ---------------------------------------------------------------- CSR build
__global__ __launch_bounds__(256) void k_hist(const int* __restrict__ dst,
                                              int* __restrict__ counts) {
    int e = blockIdx.x * 256 + threadIdx.x;
    if (e < NE) atomicAdd(&counts[dst[e]], 1);
}

// single-block exclusive scan of counts[NN] -> rowptr[NN+1], cursor[NN]
__global__ __launch_bounds__(1024) void k_scan(const int* __restrict__ counts,
                                               int* __restrict__ rowptr,
                                               int* __restrict__ cursor) {
    __shared__ int part[1024];
    int tid = threadIdx.x;
    const int CH = (NN + 1023) / 1024;   // 98
    int base = tid * CH;
    int s = 0;
    for (int i = 0; i < CH; ++i) {
        int idx = base + i;
        if (idx < NN) s += counts[idx];
    }
    part[tid] = s;
    __syncthreads();
    for (int off = 1; off < 1024; off <<= 1) {
        int t = (tid >= off) ? part[tid - off] : 0;
        __syncthreads();
        part[tid] += t;
        __syncthreads();
    }
    int run = part[tid] - s;             // exclusive prefix of this chunk
    for (int i = 0; i < CH; ++i) {
        int idx = base + i;
        if (idx < NN) {
            rowptr[idx] = run;
            cursor[idx] = run;
            run += counts[idx];
        }
    }
    if (tid == 0) rowptr[NN] = part[1023];
}

__global__ __launch_bounds__(256) void k_scatter(const int* __restrict__ src,
                                                 const int* __restrict__ dst,
                                                 int* __restrict__ cursor,
                                                 int* __restrict__ eid,
                                                 int* __restrict__ psrc) {
    int e = blockIdx.x * 256 + threadIdx.x;
    if (e >= NE) return;
    int d = dst[e];
    int pos = atomicAdd(&cursor[d], 1);
    eid[pos]  = e;
    psrc[pos] = src[e];
}

// ---------------------------------------------------------------- msg GEMV
// msg[e] = ea[e] @ W + b   (no relu, coalesced read/write, weights in LDS)
__global__ __launch_bounds__(256) void k_msg(
    const float* __restrict__ ea, const float* __restrict__ W,
    const float* __restrict__ bias, float* __restrict__ msg)
{
    __shared__ __align__(16) float Wl[DD * DD];
    __shared__ __align__(16) float bl[DD];
    int tid = threadIdx.x;
    for (int i = tid; i < DD * DD / 4; i += 256)
        ((float4*)Wl)[i] = ((const float4*)W)[i];
    if (tid < DD / 4) ((float4*)bl)[tid] = ((const float4*)bias)[tid];
    __syncthreads();

    int e = blockIdx.x * 256 + tid;      // NE % 256 == 0
    float av[DD];
    const float4* earow = (const float4*)(ea + (size_t)e * DD);
#pragma unroll
    for (int i = 0; i < DD / 4; ++i) {
        float4 t = earow[i];
        av[4*i] = t.x; av[4*i+1] = t.y; av[4*i+2] = t.z; av[4*i+3] = t.w;
    }
    float4* mrow = (float4*)(msg + (size_t)e * DD);
    for (int c4 = 0; c4 < DD / 4; ++c4) {
        float4 acc = ((float4*)bl)[c4];
#pragma unroll
        for (int k = 0; k < DD; ++k) {
            float4 w = ((float4*)Wl)[k * (DD/4) + c4];   // wave-uniform broadcast
            acc.x = fmaf(av[k], w.x, acc.x);
            acc.y = fmaf(av[k], w.y, acc.y);
            acc.z = fmaf(av[k], w.z, acc.z);
            acc.w = fmaf(av[k], w.w, acc.w);
        }
        mrow[c4] = acc;
    }
}

// ---------------------------------------------------------------- aggregate
// one wave per node; lane = channel. agg[n] = h[n] + sum relu(h[psrc]+msg[eid])
__global__ __launch_bounds__(256) void k_agg(
    const float* __restrict__ msg, const float* __restrict__ h,
    const int* __restrict__ rowptr, const int* __restrict__ eid,
    const int* __restrict__ psrc, float* __restrict__ agg)
{
    int wave = (blockIdx.x * 256 + threadIdx.x) >> 6;
    int lane = threadIdx.x & 63;
    if (wave >= NN) return;
    int beg = rowptr[wave], end = rowptr[wave + 1];
    float acc = h[(size_t)wave * DD + lane];
    for (int j = beg; j < end; ++j) {
        int e = eid[j];                  // wave-uniform broadcast load
        int s = psrc[j];
        float m = h[(size_t)s * DD + lane] + msg[(size_t)e * DD + lane];
        acc += fmaxf(m, 0.f);
    }
    agg[(size_t)wave * DD + lane] = acc;
}

// ---------------------------------------------------------------- node GEMV+relu
__global__ __launch_bounds__(256) void k_gemv_relu(
    const float* in, const float* __restrict__ W,
    const float* __restrict__ bias, float* out)
{
    __shared__ __align__(16) float Wl[DD * DD];
    __shared__ __align__(16) float bl[DD];
    int tid = threadIdx.x;
    for (int i = tid; i < DD * DD / 4; i += 256)
        ((float4*)Wl)[i] = ((const float4*)W)[i];
    if (tid < DD / 4) ((float4*)bl)[tid] = ((const float4*)bias)[tid];
    __syncthreads();

    int n = blockIdx.x * 256 + tid;
    if (n >= NN) return;

    float xr[DD];
    const float4* inrow = (const float4*)(in + (size_t)n * DD);
#pragma unroll
    for (int i = 0; i < DD / 4; ++i) {
        float4 t = inrow[i];
        xr[4*i] = t.x; xr[4*i+1] = t.y; xr[4*i+2] = t.z; xr[4*i+3] = t.w;
    }
    float4* outrow = (float4*)(out + (size_t)n * DD);
    for (int c4 = 0; c4 < DD / 4; ++c4) {
        float4 acc = ((float4*)bl)[c4];
#pragma unroll
        for (int k = 0; k < DD; ++k) {
            float4 w = ((float4*)Wl)[k * (DD/4) + c4];
            acc.x = fmaf(xr[k], w.x, acc.x);
            acc.y = fmaf(xr[k], w.y, acc.y);
            acc.z = fmaf(xr[k], w.z, acc.z);
            acc.w = fmaf(xr[k], w.w, acc.w);
        }
        float4 o;
        o.x = fmaxf(acc.x, 0.f); o.y = fmaxf(acc.y, 0.f);
        o.z = fmaxf(acc.z, 0.f); o.w = fmaxf(acc.w, 0.f);
        outrow[c4] = o;
    }
}

// ---------------------------------------------------------------- BN stats
__global__ __launch_bounds__(256) void k_stats(const float* __restrict__ z,
                                               float* __restrict__ stats) {
    int tid = threadIdx.x;
    int c = tid & 63;
    float s = 0.f, s2 = 0.f;
    for (int n = blockIdx.x * 4 + (tid >> 6); n < NN; n += 1024) {
        float v = z[(size_t)n * DD + c];
        s += v;
        s2 = fmaf(v, v, s2);
    }
    __shared__ float red[512];
    red[tid] = s; red[256 + tid] = s2;
    __syncthreads();
    if (tid < 64) {
        float a = red[tid] + red[64+tid] + red[128+tid] + red[192+tid];
        float b = red[256+tid] + red[320+tid] + red[384+tid] + red[448+tid];
        atomicAdd(&stats[c], a);
        atomicAdd(&stats[64 + c], b);
    }
}

__global__ void k_bnfinal(float* __restrict__ stats,
                          const float* __restrict__ gamma,
                          const float* __restrict__ beta) {
    int c = threadIdx.x;  // 64
    float mu  = stats[c] * (1.0f / NN);
    float var = stats[64 + c] * (1.0f / NN) - mu * mu;
    float rstd = rsqrtf(var + 1e-5f);
    float sc = gamma[c] * rstd;
    stats[c] = sc;
    stats[64 + c] = beta[c] - sc * mu;
}

// ---------------------------------------------------------------- norm + pool
__global__ __launch_bounds__(256) void k_norm_pool(
    const float* __restrict__ z, const float* __restrict__ stats,
    const int* __restrict__ batch, float* __restrict__ hout,
    float* __restrict__ pooled, int l)
{
    int total = NN * DD / 4;
    for (int i = blockIdx.x * 256 + threadIdx.x; i < total; i += gridDim.x * 256) {
        int n  = i >> 4;
        int c4 = i & 15;
        float4 v  = ((const float4*)z)[i];
        float4 sc = ((const float4*)stats)[c4];
        float4 sh = ((const float4*)stats)[16 + c4];
        float4 o;
        o.x = fmaf(v.x, sc.x, sh.x);
        o.y = fmaf(v.y, sc.y, sh.y);
        o.z = fmaf(v.z, sc.z, sh.z);
        o.w = fmaf(v.w, sc.w, sh.w);
        ((float4*)hout)[i] = o;
        int g = batch[n];
        float* pp = pooled + (size_t)g * (3 * DD) + l * DD + c4 * 4;
        atomicAdd(pp + 0, o.x);
        atomicAdd(pp + 1, o.y);
        atomicAdd(pp + 2, o.z);
        atomicAdd(pp + 3, o.w);
    }
}

// ---------------------------------------------------------------- fallback edge
__global__ __launch_bounds__(256) void k_copy(const float* __restrict__ src,
                                              float* __restrict__ agg) {
    int total = NN * DD / 4;
    for (int i = blockIdx.x * 256 + threadIdx.x; i < total; i += gridDim.x * 256)
        ((float4*)agg)[i] = ((const float4*)src)[i];
}
__global__ __launch_bounds__(256) void k_edge(
    const float* __restrict__ ea, const float* __restrict__ h,
    const float* __restrict__ W, const float* __restrict__ bias,
    const int* __restrict__ src, const int* __restrict__ dst,
    float* __restrict__ agg)
{
    __shared__ __align__(16) float Wl[DD * DD];
    __shared__ __align__(16) float bl[DD];
    int tid = threadIdx.x;
    for (int i = tid; i < DD * DD / 4; i += 256)
        ((float4*)Wl)[i] = ((const float4*)W)[i];
    if (tid < DD / 4) ((float4*)bl)[tid] = ((const float4*)bias)[tid];
    __syncthreads();

    int e = blockIdx.x * 256 + tid;
    int s = src[e], d = dst[e];
    float av[DD];
    const float4* earow = (const float4*)(ea + (size_t)e * DD);
#pragma unroll
    for (int i = 0; i < DD / 4; ++i) {
        float4 t = earow[i];
        av[4*i] = t.x; av[4*i+1] = t.y; av[4*i+2] = t.z; av[4*i+3] = t.w;
    }
    const float4* hrow = (const float4*)(h + (size_t)s * DD);
    float* arow = agg + (size_t)d * DD;
    for (int c4 = 0; c4 < DD / 4; ++c4) {
        float4 acc = ((float4*)bl)[c4];
#pragma unroll
        for (int k = 0; k < DD; ++k) {
            float4 w = ((float4*)Wl)[k * (DD/4) + c4];
            acc.x = fmaf(av[k], w.x, acc.x);
            acc.y = fmaf(av[k], w.y, acc.y);
            acc.z = fmaf(av[k], w.z, acc.z);
            acc.w = fmaf(av[k], w.w, acc.w);
        }
        float4 hv = hrow[c4];
        atomicAdd(arow + c4*4 + 0, fmaxf(hv.x + acc.x, 0.f));
        atomicAdd(arow + c4*4 + 1, fmaxf(hv.y + acc.y, 0.f));
        atomicAdd(arow + c4*4 + 2, fmaxf(hv.z + acc.z, 0.f));
        atomicAdd(arow + c4*4 + 3, fmaxf(hv.w + acc.w, 0.f));
    }
}

// ----------------------------------------------------------------------------
extern "C" void kernel_launch(void* const* d_in, const int* in_sizes, int n_in,
                              void* d_out, int out_size, void* d_ws, size_t ws_size,
                              hipStream_t stream) {
    const float* x     = (const float*)d_in[0];
    const float* ea    = (const float*)d_in[1];
    const float* We    = (const float*)d_in[2];
    const float* be    = (const float*)d_in[3];
    const float* W1    = (const float*)d_in[4];
    const float* b1    = (const float*)d_in[5];
    const float* W2    = (const float*)d_in[6];
    const float* b2    = (const float*)d_in[7];
    const float* gamma = (const float*)d_in[8];
    const float* beta  = (const float*)d_in[9];
    const int*   eidx  = (const int*)d_in[10];
    const int*   batch = (const int*)d_in[11];
    const int* src = eidx;            // edge_index[0]
    const int* dst = eidx + NE;       // edge_index[1]

    float* out_pool = (float*)d_out;                  // [NG, 3*DD]
    float* out_h    = out_pool + POOLED_F;            // [NN, DD]

    const int exp_sizes[12] = {6400000, 102400000, 12288, 192, 12288, 192,
                               12288, 192, 192, 192, 3200000, 100000};
    bool ok = (n_in == 12);
    for (int i = 0; ok && i < 12; ++i) ok = (in_sizes[i] == exp_sizes[i]);
    if (!ok) {
        k_sentinel<<<1, 64, 0, stream>>>((float*)d_out, 16384.0f);
        return;
    }

    // ---- fast-path ws layout ----
    float* msg    = (float*)d_ws;                         // NE*DD f32 (409.6 MB)
    float* agg    = msg + (size_t)NE * DD;                // NN*DD f32
    float* stats  = agg + (size_t)NN * DD;                // STATS_F
    int*   rowptr = (int*)(stats + STATS_F);              // NN+1
    int*   cursor = rowptr + (NN + 1);                    // NN
    int*   counts = cursor + NN;                          // NN
    int*   eid    = counts + NN;                          // NE
    int*   psrc   = eid + NE;                             // NE
    size_t needed_fast = ((size_t)NE * DD + (size_t)NN * DD + STATS_F) * 4
                       + ((size_t)(NN + 1) + NN + NN + NE + NE) * 4;

    k_zero<<<(POOLED_F + 255) / 256, 256, 0, stream>>>(out_pool, POOLED_F);

    if (ws_size >= needed_fast) {
        // ---------- FAST PATH: CSR gather, no global atomics ----------
        k_zero<<<(STATS_F + 255) / 256, 256, 0, stream>>>(stats, STATS_F);
        k_zeroi<<<(NN + 255) / 256, 256, 0, stream>>>(counts, NN);
        k_hist<<<NE / 256, 256, 0, stream>>>(dst, counts);
        k_scan<<<1, 1024, 0, stream>>>(counts, rowptr, cursor);
        k_scatter<<<NE / 256, 256, 0, stream>>>(src, dst, cursor, eid, psrc);

        for (int l = 0; l < 3; ++l) {
            const float* h = (l == 0) ? x : out_h;
            k_msg<<<NE / 256, 256, 0, stream>>>(ea, We + l * DD * DD,
                                                be + l * DD, msg);
            k_agg<<<(NN * DD + 255) / 256, 256, 0, stream>>>(msg, h, rowptr,
                                                             eid, psrc, agg);
            k_gemv_relu<<<(NN + 255) / 256, 256, 0, stream>>>(agg, W1 + l * DD * DD,
                                                              b1 + l * DD, agg);
            k_gemv_relu<<<(NN + 255) / 256, 256, 0, stream>>>(agg, W2 + l * DD * DD,
                                                              b2 + l * DD, agg);
            k_stats<<<256, 256, 0, stream>>>(agg, stats + l * 128);
            k_bnfinal<<<1, 64, 0, stream>>>(stats + l * 128, gamma + l * DD,
                                            beta + l * DD);
            k_norm_pool<<<2048, 256, 0, stream>>>(agg, stats + l * 128, batch,
                                                  out_h, out_pool, l);
        }
    } else {
        // ---------- FALLBACK: round-8 proven path ----------
        float* agg2   = (float*)d_ws;
        float* stats2 = agg2 + (size_t)NN * DD;
        if (ws_size < ((size_t)NN * DD + STATS_F) * sizeof(float)) {
            k_sentinel<<<1, 64, 0, stream>>>((float*)d_out, 32768.0f);
            return;
        }
        k_zero<<<(STATS_F + 255) / 256, 256, 0, stream>>>(stats2, STATS_F);
        for (int l = 0; l < 3; ++l) {
            const float* h = (l == 0) ? x : out_h;
            k_copy<<<2048, 256, 0, stream>>>(h, agg2);
            k_edge<<<NE / 256, 256, 0, stream>>>(ea, h, We + l * DD * DD,
                                                 be + l * DD, src, dst, agg2);
            k_gemv_relu<<<(NN + 255) / 256, 256, 0, stream>>>(agg2, W1 + l * DD * DD,
                                                              b1 + l * DD, agg2);
            k_gemv_relu<<<(NN + 255) / 256, 256, 0, stream>>>(agg2, W2 + l * DD * DD,
                                                              b2 + l * DD, agg2);
            k_stats<<<256, 256, 0, stream>>>(agg2, stats2 + l * 128);
            k_bnfinal<<<1, 64, 0, stream>>>(stats2 + l * 128, gamma + l * DD,
                                            beta + l * DD);
            k_norm_pool<<<2048, 256, 0, stream>>>(agg2, stats2 + l * 128, batch,
                                                  out_h, out_pool, l);
        }
    }
}

// Round 10
// 2750.970 us; speedup vs baseline: 6.0255x; 1.2088x over previous
//
#include <hip/hip_runtime.h>
#include <hip/hip_bf16.h>

#define NN 100000
#define NE 1600000
#define DD 64
#define NG 512
#define POOLED_F (NG * 3 * DD)   // 98304
#define STATS_F  (3 * 128)

__global__ __launch_bounds__(256) void k_zero(float* __restrict__ p, int n) {
    int i = blockIdx.x * 256 + threadIdx.x;
    if (i < n) p[i] = 0.f;
}
__global__ __launch_bounds__(256) void k_zeroi(int* __restrict__ p, int n) {
    int i = blockIdx.x * 256 + threadIdx.x;
    if (i < n) p[i] = 0;
}
__global__ __launch_bounds__(256) void k_sentinel(float* out, float val) {
    if (threadIdx.x == 0 && blockIdx.x == 0) out[0] = val;
}

// ---------------------------------------------------------------- CSR build
__global__ __launch_bounds__(256) void k_hist(const int* __restrict__ dst,
                                              int* __restrict__ counts) {
    int e = blockIdx.x * 256 + threadIdx.x;
    if (e < NE) atomicAdd(&counts[dst[e]], 1);
}

__global__ __launch_bounds__(1024) void k_scan(const int* __restrict__ counts,
                                               int* __restrict__ rowptr,
                                               int* __restrict__ cursor) {
    __shared__ int part[1024];
    int tid = threadIdx.x;
    const int CH = (NN + 1023) / 1024;   // 98
    int base = tid * CH;
    int s = 0;
    for (int i = 0; i < CH; ++i) {
        int idx = base + i;
        if (idx < NN) s += counts[idx];
    }
    part[tid] = s;
    __syncthreads();
    for (int off = 1; off < 1024; off <<= 1) {
        int t = (tid >= off) ? part[tid - off] : 0;
        __syncthreads();
        part[tid] += t;
        __syncthreads();
    }
    int run = part[tid] - s;
    for (int i = 0; i < CH; ++i) {
        int idx = base + i;
        if (idx < NN) {
            rowptr[idx] = run;
            cursor[idx] = run;
            run += counts[idx];
        }
    }
    if (tid == 0) rowptr[NN] = part[1023];
}

// epos[e] = CSR position of edge e; psrc[pos] = src of that edge
__global__ __launch_bounds__(256) void k_scatter(const int* __restrict__ src,
                                                 const int* __restrict__ dst,
                                                 int* __restrict__ cursor,
                                                 int* __restrict__ epos,
                                                 int* __restrict__ psrc) {
    int e = blockIdx.x * 256 + threadIdx.x;
    if (e >= NE) return;
    int pos = atomicAdd(&cursor[dst[e]], 1);
    epos[e] = pos;
    psrc[pos] = src[e];
}

// ---------------------------------------------------------------- msg GEMV v2
// Tile: 16 edge-rows per iteration, 256 threads; thread (r=tid/16, q=tid%16)
// computes channels q*4..q*4+3 of row r. Writes CSR-permuted: msg[epos[e]].
// Wave writes 4 complete contiguous rows (1KB) per store instr.
__global__ __launch_bounds__(256) void k_msg(
    const float* __restrict__ ea, const float* __restrict__ W,
    const float* __restrict__ bias, const int* __restrict__ epos,
    float* __restrict__ msg)
{
    __shared__ __align__(16) float Wl[DD * DD];       // 16 KB
    __shared__ __align__(16) float bl[DD];
    __shared__ __align__(16) float eal[16][DD + 4];   // pad: +1 bank-group/row
    int tid = threadIdx.x;
    for (int i = tid; i < DD * DD / 4; i += 256)
        ((float4*)Wl)[i] = ((const float4*)W)[i];
    if (tid < DD / 4) ((float4*)bl)[tid] = ((const float4*)bias)[tid];

    const int ntiles = NE / 16;                       // 100000
    int r = tid >> 4, q = tid & 15;

    for (int tile = blockIdx.x; tile < ntiles; tile += gridDim.x) {
        __syncthreads();   // protect eal (prev readers) / first iter: Wl pending
        {
            float4 t = ((const float4*)ea)[(size_t)tile * 256 + tid];
            int rr = tid >> 4, qq = tid & 15;
            eal[rr][qq * 4 + 0] = t.x;
            eal[rr][qq * 4 + 1] = t.y;
            eal[rr][qq * 4 + 2] = t.z;
            eal[rr][qq * 4 + 3] = t.w;
        }
        __syncthreads();   // eal + Wl ready

        float4 acc = ((float4*)bl)[q];
#pragma unroll
        for (int k = 0; k < DD; ++k) {
            float a = eal[r][k];                       // broadcast in 16-group
            float4 w = ((float4*)Wl)[k * (DD / 4) + q];
            acc.x = fmaf(a, w.x, acc.x);
            acc.y = fmaf(a, w.y, acc.y);
            acc.z = fmaf(a, w.z, acc.z);
            acc.w = fmaf(a, w.w, acc.w);
        }
        int pos = epos[tile * 16 + r];
        ((float4*)(msg + (size_t)pos * DD))[q] = acc;
    }
}

// ---------------------------------------------------------------- aggregate
// one wave per node; lane = channel; msg read is SEQUENTIAL (CSR order)
__global__ __launch_bounds__(256) void k_agg(
    const float* __restrict__ msg, const float* __restrict__ h,
    const int* __restrict__ rowptr, const int* __restrict__ psrc,
    float* __restrict__ agg)
{
    int node = (blockIdx.x * 256 + threadIdx.x) >> 6;
    int lane = threadIdx.x & 63;
    if (node >= NN) return;
    int beg = rowptr[node], end = rowptr[node + 1];
    float acc = h[(size_t)node * DD + lane];
    int j = beg;
    for (; j + 1 < end; j += 2) {
        int s0 = psrc[j], s1 = psrc[j + 1];
        float m0 = h[(size_t)s0 * DD + lane] + msg[(size_t)j * DD + lane];
        float m1 = h[(size_t)s1 * DD + lane] + msg[(size_t)(j + 1) * DD + lane];
        acc += fmaxf(m0, 0.f) + fmaxf(m1, 0.f);
    }
    if (j < end) {
        int s = psrc[j];
        acc += fmaxf(h[(size_t)s * DD + lane] + msg[(size_t)j * DD + lane], 0.f);
    }
    agg[(size_t)node * DD + lane] = acc;
}

// ---------------------------------------------------------------- fused MLP
// out = relu(relu(in@W1+b1)@W2+b2), in-place safe
__global__ __launch_bounds__(256) void k_mlp(
    const float* in, const float* __restrict__ W1, const float* __restrict__ b1,
    const float* __restrict__ W2, const float* __restrict__ b2, float* out)
{
    __shared__ __align__(16) float W1l[DD * DD];
    __shared__ __align__(16) float W2l[DD * DD];
    __shared__ __align__(16) float b1l[DD];
    __shared__ __align__(16) float b2l[DD];
    int tid = threadIdx.x;
    for (int i = tid; i < DD * DD / 4; i += 256) {
        ((float4*)W1l)[i] = ((const float4*)W1)[i];
        ((float4*)W2l)[i] = ((const float4*)W2)[i];
    }
    if (tid < DD / 4) {
        ((float4*)b1l)[tid] = ((const float4*)b1)[tid];
        ((float4*)b2l)[tid] = ((const float4*)b2)[tid];
    }
    __syncthreads();

    int n = blockIdx.x * 256 + tid;
    if (n >= NN) return;

    float xr[DD];
    const float4* inrow = (const float4*)(in + (size_t)n * DD);
#pragma unroll
    for (int i = 0; i < DD / 4; ++i) {
        float4 t = inrow[i];
        xr[4*i] = t.x; xr[4*i+1] = t.y; xr[4*i+2] = t.z; xr[4*i+3] = t.w;
    }
    float z1[DD];
    for (int c4 = 0; c4 < DD / 4; ++c4) {
        float4 acc = ((float4*)b1l)[c4];
#pragma unroll
        for (int k = 0; k < DD; ++k) {
            float4 w = ((float4*)W1l)[k * (DD/4) + c4];
            acc.x = fmaf(xr[k], w.x, acc.x);
            acc.y = fmaf(xr[k], w.y, acc.y);
            acc.z = fmaf(xr[k], w.z, acc.z);
            acc.w = fmaf(xr[k], w.w, acc.w);
        }
        z1[c4*4+0] = fmaxf(acc.x, 0.f);
        z1[c4*4+1] = fmaxf(acc.y, 0.f);
        z1[c4*4+2] = fmaxf(acc.z, 0.f);
        z1[c4*4+3] = fmaxf(acc.w, 0.f);
    }
    float4* outrow = (float4*)(out + (size_t)n * DD);
    for (int c4 = 0; c4 < DD / 4; ++c4) {
        float4 acc = ((float4*)b2l)[c4];
#pragma unroll
        for (int k = 0; k < DD; ++k) {
            float4 w = ((float4*)W2l)[k * (DD/4) + c4];
            acc.x = fmaf(z1[k], w.x, acc.x);
            acc.y = fmaf(z1[k], w.y, acc.y);
            acc.z = fmaf(z1[k], w.z, acc.z);
            acc.w = fmaf(z1[k], w.w, acc.w);
        }
        float4 o;
        o.x = fmaxf(acc.x, 0.f); o.y = fmaxf(acc.y, 0.f);
        o.z = fmaxf(acc.z, 0.f); o.w = fmaxf(acc.w, 0.f);
        outrow[c4] = o;
    }
}

// ---------------------------------------------------------------- BN stats
__global__ __launch_bounds__(256) void k_stats(const float* __restrict__ z,
                                               float* __restrict__ stats) {
    int tid = threadIdx.x;
    int c = tid & 63;
    float s = 0.f, s2 = 0.f;
    for (int n = blockIdx.x * 4 + (tid >> 6); n < NN; n += 1024) {
        float v = z[(size_t)n * DD + c];
        s += v;
        s2 = fmaf(v, v, s2);
    }
    __shared__ float red[512];
    red[tid] = s; red[256 + tid] = s2;
    __syncthreads();
    if (tid < 64) {
        float a = red[tid] + red[64+tid] + red[128+tid] + red[192+tid];
        float b = red[256+tid] + red[320+tid] + red[384+tid] + red[448+tid];
        atomicAdd(&stats[c], a);
        atomicAdd(&stats[64 + c], b);
    }
}

__global__ void k_bnfinal(float* __restrict__ stats,
                          const float* __restrict__ gamma,
                          const float* __restrict__ beta) {
    int c = threadIdx.x;  // 64
    float mu  = stats[c] * (1.0f / NN);
    float var = stats[64 + c] * (1.0f / NN) - mu * mu;
    float rstd = rsqrtf(var + 1e-5f);
    float sc = gamma[c] * rstd;
    stats[c] = sc;
    stats[64 + c] = beta[c] - sc * mu;
}

// ---------------------------------------------------------------- norm + pool
__global__ __launch_bounds__(256) void k_norm_pool(
    const float* __restrict__ z, const float* __restrict__ stats,
    const int* __restrict__ batch, float* __restrict__ hout,
    float* __restrict__ pooled, int l)
{
    int total = NN * DD / 4;
    for (int i = blockIdx.x * 256 + threadIdx.x; i < total; i += gridDim.x * 256) {
        int n  = i >> 4;
        int c4 = i & 15;
        float4 v  = ((const float4*)z)[i];
        float4 sc = ((const float4*)stats)[c4];
        float4 sh = ((const float4*)stats)[16 + c4];
        float4 o;
        o.x = fmaf(v.x, sc.x, sh.x);
        o.y = fmaf(v.y, sc.y, sh.y);
        o.z = fmaf(v.z, sc.z, sh.z);
        o.w = fmaf(v.w, sc.w, sh.w);
        ((float4*)hout)[i] = o;
        int g = batch[n];
        float* pp = pooled + (size_t)g * (3 * DD) + l * DD + c4 * 4;
        atomicAdd(pp + 0, o.x);
        atomicAdd(pp + 1, o.y);
        atomicAdd(pp + 2, o.z);
        atomicAdd(pp + 3, o.w);
    }
}

// ---------------------------------------------------------------- fallback
__global__ __launch_bounds__(256) void k_copy(const float* __restrict__ src,
                                              float* __restrict__ agg) {
    int total = NN * DD / 4;
    for (int i = blockIdx.x * 256 + threadIdx.x; i < total; i += gridDim.x * 256)
        ((float4*)agg)[i] = ((const float4*)src)[i];
}
__global__ __launch_bounds__(256) void k_edge(
    const float* __restrict__ ea, const float* __restrict__ h,
    const float* __restrict__ W, const float* __restrict__ bias,
    const int* __restrict__ src, const int* __restrict__ dst,
    float* __restrict__ agg)
{
    __shared__ __align__(16) float Wl[DD * DD];
    __shared__ __align__(16) float bl[DD];
    int tid = threadIdx.x;
    for (int i = tid; i < DD * DD / 4; i += 256)
        ((float4*)Wl)[i] = ((const float4*)W)[i];
    if (tid < DD / 4) ((float4*)bl)[tid] = ((const float4*)bias)[tid];
    __syncthreads();
    int e = blockIdx.x * 256 + tid;
    int s = src[e], d = dst[e];
    float av[DD];
    const float4* earow = (const float4*)(ea + (size_t)e * DD);
#pragma unroll
    for (int i = 0; i < DD / 4; ++i) {
        float4 t = earow[i];
        av[4*i] = t.x; av[4*i+1] = t.y; av[4*i+2] = t.z; av[4*i+3] = t.w;
    }
    const float4* hrow = (const float4*)(h + (size_t)s * DD);
    float* arow = agg + (size_t)d * DD;
    for (int c4 = 0; c4 < DD / 4; ++c4) {
        float4 acc = ((float4*)bl)[c4];
#pragma unroll
        for (int k = 0; k < DD; ++k) {
            float4 w = ((float4*)Wl)[k * (DD/4) + c4];
            acc.x = fmaf(av[k], w.x, acc.x);
            acc.y = fmaf(av[k], w.y, acc.y);
            acc.z = fmaf(av[k], w.z, acc.z);
            acc.w = fmaf(av[k], w.w, acc.w);
        }
        float4 hv = hrow[c4];
        atomicAdd(arow + c4*4 + 0, fmaxf(hv.x + acc.x, 0.f));
        atomicAdd(arow + c4*4 + 1, fmaxf(hv.y + acc.y, 0.f));
        atomicAdd(arow + c4*4 + 2, fmaxf(hv.z + acc.z, 0.f));
        atomicAdd(arow + c4*4 + 3, fmaxf(hv.w + acc.w, 0.f));
    }
}

// ----------------------------------------------------------------------------
extern "C" void kernel_launch(void* const* d_in, const int* in_sizes, int n_in,
                              void* d_out, int out_size, void* d_ws, size_t ws_size,
                              hipStream_t stream) {
    const float* x     = (const float*)d_in[0];
    const float* ea    = (const float*)d_in[1];
    const float* We    = (const float*)d_in[2];
    const float* be    = (const float*)d_in[3];
    const float* W1    = (const float*)d_in[4];
    const float* b1    = (const float*)d_in[5];
    const float* W2    = (const float*)d_in[6];
    const float* b2    = (const float*)d_in[7];
    const float* gamma = (const float*)d_in[8];
    const float* beta  = (const float*)d_in[9];
    const int*   eidx  = (const int*)d_in[10];
    const int*   batch = (const int*)d_in[11];
    const int* src = eidx;
    const int* dst = eidx + NE;

    float* out_pool = (float*)d_out;                  // [NG, 3*DD]
    float* out_h    = out_pool + POOLED_F;            // [NN, DD]

    const int exp_sizes[12] = {6400000, 102400000, 12288, 192, 12288, 192,
                               12288, 192, 192, 192, 3200000, 100000};
    bool ok = (n_in == 12);
    for (int i = 0; ok && i < 12; ++i) ok = (in_sizes[i] == exp_sizes[i]);
    if (!ok) {
        k_sentinel<<<1, 64, 0, stream>>>((float*)d_out, 16384.0f);
        return;
    }

    float* msg    = (float*)d_ws;                         // NE*DD f32
    float* agg    = msg + (size_t)NE * DD;                // NN*DD f32
    float* stats  = agg + (size_t)NN * DD;                // STATS_F
    int*   rowptr = (int*)(stats + STATS_F);              // NN+1
    int*   cursor = rowptr + (NN + 1);                    // NN
    int*   counts = cursor + NN;                          // NN
    int*   epos   = counts + NN;                          // NE
    int*   psrc   = epos + NE;                            // NE
    size_t needed_fast = ((size_t)NE * DD + (size_t)NN * DD + STATS_F) * 4
                       + ((size_t)(NN + 1) + NN + NN + NE + NE) * 4;

    k_zero<<<(POOLED_F + 255) / 256, 256, 0, stream>>>(out_pool, POOLED_F);

    if (ws_size >= needed_fast) {
        k_zero<<<(STATS_F + 255) / 256, 256, 0, stream>>>(stats, STATS_F);
        k_zeroi<<<(NN + 255) / 256, 256, 0, stream>>>(counts, NN);
        k_hist<<<NE / 256, 256, 0, stream>>>(dst, counts);
        k_scan<<<1, 1024, 0, stream>>>(counts, rowptr, cursor);
        k_scatter<<<NE / 256, 256, 0, stream>>>(src, dst, cursor, epos, psrc);

        for (int l = 0; l < 3; ++l) {
            const float* h = (l == 0) ? x : out_h;
            k_msg<<<4096, 256, 0, stream>>>(ea, We + l * DD * DD, be + l * DD,
                                            epos, msg);
            k_agg<<<(NN * DD + 255) / 256, 256, 0, stream>>>(msg, h, rowptr,
                                                             psrc, agg);
            k_mlp<<<(NN + 255) / 256, 256, 0, stream>>>(agg, W1 + l * DD * DD,
                                                        b1 + l * DD,
                                                        W2 + l * DD * DD,
                                                        b2 + l * DD, agg);
            k_stats<<<256, 256, 0, stream>>>(agg, stats + l * 128);
            k_bnfinal<<<1, 64, 0, stream>>>(stats + l * 128, gamma + l * DD,
                                            beta + l * DD);
            k_norm_pool<<<2048, 256, 0, stream>>>(agg, stats + l * 128, batch,
                                                  out_h, out_pool, l);
        }
    } else {
        // fallback: round-8 proven path
        float* agg2   = (float*)d_ws;
        float* stats2 = agg2 + (size_t)NN * DD;
        if (ws_size < ((size_t)NN * DD + STATS_F) * sizeof(float)) {
            k_sentinel<<<1, 64, 0, stream>>>((float*)d_out, 32768.0f);
            return;
        }
        k_zero<<<(STATS_F + 255) / 256, 256, 0, stream>>>(stats2, STATS_F);
        for (int l = 0; l < 3; ++l) {
            const float* h = (l == 0) ? x : out_h;
            k_copy<<<2048, 256, 0, stream>>>(h, agg2);
            k_edge<<<NE / 256, 256, 0, stream>>>(ea, h, We + l * DD * DD,
                                                 be + l * DD, src, dst, agg2);
            k_mlp<<<(NN + 255) / 256, 256, 0, stream>>>(agg2, W1 + l * DD * DD,
                                                        b1 + l * DD,
                                                        W2 + l * DD * DD,
                                                        b2 + l * DD, agg2);
            k_stats<<<256, 256, 0, stream>>>(agg2, stats2 + l * 128);
            k_bnfinal<<<1, 64, 0, stream>>>(stats2 + l * 128, gamma + l * DD,
                                            beta + l * DD);
            k_norm_pool<<<2048, 256, 0, stream>>>(agg2, stats2 + l * 128, batch,
                                                  out_h, out_pool, l);
        }
    }
}

// Round 11
// 1895.013 us; speedup vs baseline: 8.7471x; 1.4517x over previous
//
#include <hip/hip_runtime.h>
#include <hip/hip_bf16.h>

#define NN 100000
#define NE 1600000
#define DD 64
#define NG 512
#define POOLED_F (NG * 3 * DD)   // 98304
#define STATS_F  (3 * 128)

__global__ __launch_bounds__(256) void k_zero(float* __restrict__ p, int n) {
    int i = blockIdx.x * 256 + threadIdx.x;
    if (i < n) p[i] = 0.f;
}
__global__ __launch_bounds__(256) void k_zeroi(int* __restrict__ p, int n) {
    int i = blockIdx.x * 256 + threadIdx.x;
    if (i < n) p[i] = 0;
}
__global__ __launch_bounds__(256) void k_sentinel(float* out, float val) {
    if (threadIdx.x == 0 && blockIdx.x == 0) out[0] = val;
}

// ---------------------------------------------------------------- CSR build
__global__ __launch_bounds__(256) void k_hist(const int* __restrict__ dst,
                                              int* __restrict__ counts) {
    int e = blockIdx.x * 256 + threadIdx.x;
    if (e < NE) atomicAdd(&counts[dst[e]], 1);
}

__global__ __launch_bounds__(1024) void k_scan(const int* __restrict__ counts,
                                               int* __restrict__ rowptr,
                                               int* __restrict__ cursor) {
    __shared__ int part[1024];
    int tid = threadIdx.x;
    const int CH = (NN + 1023) / 1024;   // 98
    int base = tid * CH;
    int s = 0;
    for (int i = 0; i < CH; ++i) {
        int idx = base + i;
        if (idx < NN) s += counts[idx];
    }
    part[tid] = s;
    __syncthreads();
    for (int off = 1; off < 1024; off <<= 1) {
        int t = (tid >= off) ? part[tid - off] : 0;
        __syncthreads();
        part[tid] += t;
        __syncthreads();
    }
    int run = part[tid] - s;
    for (int i = 0; i < CH; ++i) {
        int idx = base + i;
        if (idx < NN) {
            rowptr[idx] = run;
            cursor[idx] = run;
            run += counts[idx];
        }
    }
    if (tid == 0) rowptr[NN] = part[1023];
}

__global__ __launch_bounds__(256) void k_scatter(const int* __restrict__ src,
                                                 const int* __restrict__ dst,
                                                 int* __restrict__ cursor,
                                                 int* __restrict__ epos,
                                                 int* __restrict__ psrc) {
    int e = blockIdx.x * 256 + threadIdx.x;
    if (e >= NE) return;
    int pos = atomicAdd(&cursor[dst[e]], 1);
    epos[e] = pos;
    psrc[pos] = src[e];
}

// ---------------------------------------------------------------- msg GEMM v3
// Tile 64 edges x 64 ch; 256 threads as 16x16; thread (ty,tx) computes a 4x4
// sub-tile: edges ty*4..+3, channels tx*4..+3. ea staged TRANSPOSED in LDS
// (eaT[k][row], stride 68 keeps float4 16B-alignment). Inner loop: 2 ds_read
// _b128 -> 16 FMA. Writes CSR-permuted full rows.
#define MT 64
__global__ __launch_bounds__(256) void k_msg(
    const float* __restrict__ ea, const float* __restrict__ W,
    const float* __restrict__ bias, const int* __restrict__ epos,
    float* __restrict__ msg)
{
    __shared__ __align__(16) float Wl[DD * DD];          // 16 KB
    __shared__ __align__(16) float bl[DD];
    __shared__ __align__(16) float eaT[DD][MT + 4];      // transposed, stride 68
    int tid = threadIdx.x;
    for (int i = tid; i < DD * DD / 4; i += 256)
        ((float4*)Wl)[i] = ((const float4*)W)[i];
    if (tid < DD / 4) ((float4*)bl)[tid] = ((const float4*)bias)[tid];

    const int ntiles = NE / MT;                          // 25000
    int tx = tid & 15;           // channel group
    int ty = tid >> 4;           // edge group

    for (int tile = blockIdx.x; tile < ntiles; tile += gridDim.x) {
        __syncthreads();   // prev readers done (also covers initial Wl stage)
#pragma unroll
        for (int i = 0; i < 4; ++i) {
            int idx = i * 256 + tid;
            int row = idx >> 4, c4 = idx & 15;
            float4 t = ((const float4*)ea)[(size_t)tile * (MT * DD / 4) + idx];
            eaT[c4 * 4 + 0][row] = t.x;
            eaT[c4 * 4 + 1][row] = t.y;
            eaT[c4 * 4 + 2][row] = t.z;
            eaT[c4 * 4 + 3][row] = t.w;
        }
        __syncthreads();

        float4 b = ((float4*)bl)[tx];
        float4 acc0 = b, acc1 = b, acc2 = b, acc3 = b;
#pragma unroll 16
        for (int k = 0; k < DD; ++k) {
            float4 w = ((float4*)Wl)[k * 16 + tx];
            float4 a = *(const float4*)&eaT[k][ty * 4];
            acc0.x = fmaf(a.x, w.x, acc0.x);
            acc0.y = fmaf(a.x, w.y, acc0.y);
            acc0.z = fmaf(a.x, w.z, acc0.z);
            acc0.w = fmaf(a.x, w.w, acc0.w);
            acc1.x = fmaf(a.y, w.x, acc1.x);
            acc1.y = fmaf(a.y, w.y, acc1.y);
            acc1.z = fmaf(a.y, w.z, acc1.z);
            acc1.w = fmaf(a.y, w.w, acc1.w);
            acc2.x = fmaf(a.z, w.x, acc2.x);
            acc2.y = fmaf(a.z, w.y, acc2.y);
            acc2.z = fmaf(a.z, w.z, acc2.z);
            acc2.w = fmaf(a.z, w.w, acc2.w);
            acc3.x = fmaf(a.w, w.x, acc3.x);
            acc3.y = fmaf(a.w, w.y, acc3.y);
            acc3.z = fmaf(a.w, w.z, acc3.z);
            acc3.w = fmaf(a.w, w.w, acc3.w);
        }
        int ebase = tile * MT + ty * 4;
        int p0 = epos[ebase + 0], p1 = epos[ebase + 1];
        int p2 = epos[ebase + 2], p3 = epos[ebase + 3];
        ((float4*)(msg + (size_t)p0 * DD))[tx] = acc0;
        ((float4*)(msg + (size_t)p1 * DD))[tx] = acc1;
        ((float4*)(msg + (size_t)p2 * DD))[tx] = acc2;
        ((float4*)(msg + (size_t)p3 * DD))[tx] = acc3;
    }
}

// ---------------------------------------------------------------- aggregate
// one wave per node; lane = channel; msg read is SEQUENTIAL (CSR order)
__global__ __launch_bounds__(256) void k_agg(
    const float* __restrict__ msg, const float* __restrict__ h,
    const int* __restrict__ rowptr, const int* __restrict__ psrc,
    float* __restrict__ agg)
{
    int node = (blockIdx.x * 256 + threadIdx.x) >> 6;
    int lane = threadIdx.x & 63;
    if (node >= NN) return;
    int beg = rowptr[node], end = rowptr[node + 1];
    float acc = h[(size_t)node * DD + lane];
    int j = beg;
    for (; j + 1 < end; j += 2) {
        int s0 = psrc[j], s1 = psrc[j + 1];
        float m0 = h[(size_t)s0 * DD + lane] + msg[(size_t)j * DD + lane];
        float m1 = h[(size_t)s1 * DD + lane] + msg[(size_t)(j + 1) * DD + lane];
        acc += fmaxf(m0, 0.f) + fmaxf(m1, 0.f);
    }
    if (j < end) {
        int s = psrc[j];
        acc += fmaxf(h[(size_t)s * DD + lane] + msg[(size_t)j * DD + lane], 0.f);
    }
    agg[(size_t)node * DD + lane] = acc;
}

// ---------------------------------------------------------------- fused MLP
__global__ __launch_bounds__(256) void k_mlp(
    const float* in, const float* __restrict__ W1, const float* __restrict__ b1,
    const float* __restrict__ W2, const float* __restrict__ b2, float* out)
{
    __shared__ __align__(16) float W1l[DD * DD];
    __shared__ __align__(16) float W2l[DD * DD];
    __shared__ __align__(16) float b1l[DD];
    __shared__ __align__(16) float b2l[DD];
    int tid = threadIdx.x;
    for (int i = tid; i < DD * DD / 4; i += 256) {
        ((float4*)W1l)[i] = ((const float4*)W1)[i];
        ((float4*)W2l)[i] = ((const float4*)W2)[i];
    }
    if (tid < DD / 4) {
        ((float4*)b1l)[tid] = ((const float4*)b1)[tid];
        ((float4*)b2l)[tid] = ((const float4*)b2)[tid];
    }
    __syncthreads();

    int n = blockIdx.x * 256 + tid;
    if (n >= NN) return;

    float xr[DD];
    const float4* inrow = (const float4*)(in + (size_t)n * DD);
#pragma unroll
    for (int i = 0; i < DD / 4; ++i) {
        float4 t = inrow[i];
        xr[4*i] = t.x; xr[4*i+1] = t.y; xr[4*i+2] = t.z; xr[4*i+3] = t.w;
    }
    float z1[DD];
    for (int c4 = 0; c4 < DD / 4; ++c4) {
        float4 acc = ((float4*)b1l)[c4];
#pragma unroll
        for (int k = 0; k < DD; ++k) {
            float4 w = ((float4*)W1l)[k * (DD/4) + c4];
            acc.x = fmaf(xr[k], w.x, acc.x);
            acc.y = fmaf(xr[k], w.y, acc.y);
            acc.z = fmaf(xr[k], w.z, acc.z);
            acc.w = fmaf(xr[k], w.w, acc.w);
        }
        z1[c4*4+0] = fmaxf(acc.x, 0.f);
        z1[c4*4+1] = fmaxf(acc.y, 0.f);
        z1[c4*4+2] = fmaxf(acc.z, 0.f);
        z1[c4*4+3] = fmaxf(acc.w, 0.f);
    }
    float4* outrow = (float4*)(out + (size_t)n * DD);
    for (int c4 = 0; c4 < DD / 4; ++c4) {
        float4 acc = ((float4*)b2l)[c4];
#pragma unroll
        for (int k = 0; k < DD; ++k) {
            float4 w = ((float4*)W2l)[k * (DD/4) + c4];
            acc.x = fmaf(z1[k], w.x, acc.x);
            acc.y = fmaf(z1[k], w.y, acc.y);
            acc.z = fmaf(z1[k], w.z, acc.z);
            acc.w = fmaf(z1[k], w.w, acc.w);
        }
        float4 o;
        o.x = fmaxf(acc.x, 0.f); o.y = fmaxf(acc.y, 0.f);
        o.z = fmaxf(acc.z, 0.f); o.w = fmaxf(acc.w, 0.f);
        outrow[c4] = o;
    }
}

// ---------------------------------------------------------------- BN stats
__global__ __launch_bounds__(256) void k_stats(const float* __restrict__ z,
                                               float* __restrict__ stats) {
    int tid = threadIdx.x;
    int c = tid & 63;
    float s = 0.f, s2 = 0.f;
    for (int n = blockIdx.x * 4 + (tid >> 6); n < NN; n += 1024) {
        float v = z[(size_t)n * DD + c];
        s += v;
        s2 = fmaf(v, v, s2);
    }
    __shared__ float red[512];
    red[tid] = s; red[256 + tid] = s2;
    __syncthreads();
    if (tid < 64) {
        float a = red[tid] + red[64+tid] + red[128+tid] + red[192+tid];
        float b = red[256+tid] + red[320+tid] + red[384+tid] + red[448+tid];
        atomicAdd(&stats[c], a);
        atomicAdd(&stats[64 + c], b);
    }
}

__global__ void k_bnfinal(float* __restrict__ stats,
                          const float* __restrict__ gamma,
                          const float* __restrict__ beta) {
    int c = threadIdx.x;  // 64
    float mu  = stats[c] * (1.0f / NN);
    float var = stats[64 + c] * (1.0f / NN) - mu * mu;
    float rstd = rsqrtf(var + 1e-5f);
    float sc = gamma[c] * rstd;
    stats[c] = sc;
    stats[64 + c] = beta[c] - sc * mu;
}

// ------------------------------------------ norm + pool v2 (sorted batch)
// one wave per 64 consecutive nodes; lane = channel; register run-accumulate
// per graph, one atomic flush per boundary (batch is sorted).
__global__ __launch_bounds__(256) void k_norm_pool(
    const float* __restrict__ z, const float* __restrict__ stats,
    const int* __restrict__ batch, float* __restrict__ hout,
    float* __restrict__ pooled, int l)
{
    int wave = (blockIdx.x * 256 + threadIdx.x) >> 6;
    int lane = threadIdx.x & 63;
    int n0 = wave * 64;
    if (n0 >= NN) return;
    int n1 = n0 + 64; if (n1 > NN) n1 = NN;
    float sc = stats[lane], sh = stats[64 + lane];
    int gcur = batch[n0];
    float acc = 0.f;
    for (int n = n0; n < n1; ++n) {
        float h = fmaf(z[(size_t)n * DD + lane], sc, sh);
        hout[(size_t)n * DD + lane] = h;
        int g = batch[n];                    // wave-uniform broadcast
        if (g != gcur) {                     // uniform branch
            atomicAdd(&pooled[(size_t)gcur * (3 * DD) + l * DD + lane], acc);
            gcur = g; acc = 0.f;
        }
        acc += h;
    }
    atomicAdd(&pooled[(size_t)gcur * (3 * DD) + l * DD + lane], acc);
}

// ---------------------------------------------------------------- fallback
__global__ __launch_bounds__(256) void k_copy(const float* __restrict__ src,
                                              float* __restrict__ agg) {
    int total = NN * DD / 4;
    for (int i = blockIdx.x * 256 + threadIdx.x; i < total; i += gridDim.x * 256)
        ((float4*)agg)[i] = ((const float4*)src)[i];
}
__global__ __launch_bounds__(256) void k_edge(
    const float* __restrict__ ea, const float* __restrict__ h,
    const float* __restrict__ W, const float* __restrict__ bias,
    const int* __restrict__ src, const int* __restrict__ dst,
    float* __restrict__ agg)
{
    __shared__ __align__(16) float Wl[DD * DD];
    __shared__ __align__(16) float bl[DD];
    int tid = threadIdx.x;
    for (int i = tid; i < DD * DD / 4; i += 256)
        ((float4*)Wl)[i] = ((const float4*)W)[i];
    if (tid < DD / 4) ((float4*)bl)[tid] = ((const float4*)bias)[tid];
    __syncthreads();
    int e = blockIdx.x * 256 + tid;
    int s = src[e], d = dst[e];
    float av[DD];
    const float4* earow = (const float4*)(ea + (size_t)e * DD);
#pragma unroll
    for (int i = 0; i < DD / 4; ++i) {
        float4 t = earow[i];
        av[4*i] = t.x; av[4*i+1] = t.y; av[4*i+2] = t.z; av[4*i+3] = t.w;
    }
    const float4* hrow = (const float4*)(h + (size_t)s * DD);
    float* arow = agg + (size_t)d * DD;
    for (int c4 = 0; c4 < DD / 4; ++c4) {
        float4 acc = ((float4*)bl)[c4];
#pragma unroll
        for (int k = 0; k < DD; ++k) {
            float4 w = ((float4*)Wl)[k * (DD/4) + c4];
            acc.x = fmaf(av[k], w.x, acc.x);
            acc.y = fmaf(av[k], w.y, acc.y);
            acc.z = fmaf(av[k], w.z, acc.z);
            acc.w = fmaf(av[k], w.w, acc.w);
        }
        float4 hv = hrow[c4];
        atomicAdd(arow + c4*4 + 0, fmaxf(hv.x + acc.x, 0.f));
        atomicAdd(arow + c4*4 + 1, fmaxf(hv.y + acc.y, 0.f));
        atomicAdd(arow + c4*4 + 2, fmaxf(hv.z + acc.z, 0.f));
        atomicAdd(arow + c4*4 + 3, fmaxf(hv.w + acc.w, 0.f));
    }
}

// ----------------------------------------------------------------------------
extern "C" void kernel_launch(void* const* d_in, const int* in_sizes, int n_in,
                              void* d_out, int out_size, void* d_ws, size_t ws_size,
                              hipStream_t stream) {
    const float* x     = (const float*)d_in[0];
    const float* ea    = (const float*)d_in[1];
    const float* We    = (const float*)d_in[2];
    const float* be    = (const float*)d_in[3];
    const float* W1    = (const float*)d_in[4];
    const float* b1    = (const float*)d_in[5];
    const float* W2    = (const float*)d_in[6];
    const float* b2    = (const float*)d_in[7];
    const float* gamma = (const float*)d_in[8];
    const float* beta  = (const float*)d_in[9];
    const int*   eidx  = (const int*)d_in[10];
    const int*   batch = (const int*)d_in[11];
    const int* src = eidx;
    const int* dst = eidx + NE;

    float* out_pool = (float*)d_out;                  // [NG, 3*DD]
    float* out_h    = out_pool + POOLED_F;            // [NN, DD]

    const int exp_sizes[12] = {6400000, 102400000, 12288, 192, 12288, 192,
                               12288, 192, 192, 192, 3200000, 100000};
    bool ok = (n_in == 12);
    for (int i = 0; ok && i < 12; ++i) ok = (in_sizes[i] == exp_sizes[i]);
    if (!ok) {
        k_sentinel<<<1, 64, 0, stream>>>((float*)d_out, 16384.0f);
        return;
    }

    float* msg    = (float*)d_ws;                         // NE*DD f32
    float* agg    = msg + (size_t)NE * DD;                // NN*DD f32
    float* stats  = agg + (size_t)NN * DD;                // STATS_F
    int*   rowptr = (int*)(stats + STATS_F);              // NN+1
    int*   cursor = rowptr + (NN + 1);                    // NN
    int*   counts = cursor + NN;                          // NN
    int*   epos   = counts + NN;                          // NE
    int*   psrc   = epos + NE;                            // NE
    size_t needed_fast = ((size_t)NE * DD + (size_t)NN * DD + STATS_F) * 4
                       + ((size_t)(NN + 1) + NN + NN + NE + NE) * 4;

    k_zero<<<(POOLED_F + 255) / 256, 256, 0, stream>>>(out_pool, POOLED_F);

    if (ws_size >= needed_fast) {
        k_zero<<<(STATS_F + 255) / 256, 256, 0, stream>>>(stats, STATS_F);
        k_zeroi<<<(NN + 255) / 256, 256, 0, stream>>>(counts, NN);
        k_hist<<<NE / 256, 256, 0, stream>>>(dst, counts);
        k_scan<<<1, 1024, 0, stream>>>(counts, rowptr, cursor);
        k_scatter<<<NE / 256, 256, 0, stream>>>(src, dst, cursor, epos, psrc);

        for (int l = 0; l < 3; ++l) {
            const float* h = (l == 0) ? x : out_h;
            k_msg<<<2048, 256, 0, stream>>>(ea, We + l * DD * DD, be + l * DD,
                                            epos, msg);
            k_agg<<<(NN * DD + 255) / 256, 256, 0, stream>>>(msg, h, rowptr,
                                                             psrc, agg);
            k_mlp<<<(NN + 255) / 256, 256, 0, stream>>>(agg, W1 + l * DD * DD,
                                                        b1 + l * DD,
                                                        W2 + l * DD * DD,
                                                        b2 + l * DD, agg);
            k_stats<<<256, 256, 0, stream>>>(agg, stats + l * 128);
            k_bnfinal<<<1, 64, 0, stream>>>(stats + l * 128, gamma + l * DD,
                                            beta + l * DD);
            k_norm_pool<<<(NN + 255) / 256, 256, 0, stream>>>(agg, stats + l * 128,
                                                              batch, out_h,
                                                              out_pool, l);
        }
    } else {
        // fallback: round-8 proven path
        float* agg2   = (float*)d_ws;
        float* stats2 = agg2 + (size_t)NN * DD;
        if (ws_size < ((size_t)NN * DD + STATS_F) * sizeof(float)) {
            k_sentinel<<<1, 64, 0, stream>>>((float*)d_out, 32768.0f);
            return;
        }
        k_zero<<<(STATS_F + 255) / 256, 256, 0, stream>>>(stats2, STATS_F);
        for (int l = 0; l < 3; ++l) {
            const float* h = (l == 0) ? x : out_h;
            k_copy<<<2048, 256, 0, stream>>>(h, agg2);
            k_edge<<<NE / 256, 256, 0, stream>>>(ea, h, We + l * DD * DD,
                                                 be + l * DD, src, dst, agg2);
            k_mlp<<<(NN + 255) / 256, 256, 0, stream>>>(agg2, W1 + l * DD * DD,
                                                        b1 + l * DD,
                                                        W2 + l * DD * DD,
                                                        b2 + l * DD, agg2);
            k_stats<<<256, 256, 0, stream>>>(agg2, stats2 + l * 128);
            k_bnfinal<<<1, 64, 0, stream>>>(stats2 + l * 128, gamma + l * DD,
                                            beta + l * DD);
            k_norm_pool<<<(NN + 255) / 256, 256, 0, stream>>>(agg2, stats2 + l * 128,
                                                              batch, out_h,
                                                              out_pool, l);
        }
    }
}

// Round 12
// 1640.551 us; speedup vs baseline: 10.1038x; 1.1551x over previous
//
#include <hip/hip_runtime.h>
#include <hip/hip_bf16.h>

#define NN 100000
#define NE 1600000
#define DD 64
#define NG 512
#define POOLED_F (NG * 3 * DD)   // 98304
#define STATS_F  (3 * 128)
#define SCAN_NB 196              // 196 * 512 = 100352 >= NN

__global__ __launch_bounds__(256) void k_zero(float* __restrict__ p, int n) {
    int i = blockIdx.x * 256 + threadIdx.x;
    if (i < n) p[i] = 0.f;
}
__global__ __launch_bounds__(256) void k_zeroi(int* __restrict__ p, int n) {
    int i = blockIdx.x * 256 + threadIdx.x;
    if (i < n) p[i] = 0;
}
__global__ __launch_bounds__(256) void k_sentinel(float* out, float val) {
    if (threadIdx.x == 0 && blockIdx.x == 0) out[0] = val;
}

// ---------------------------------------------------------------- CSR build
__global__ __launch_bounds__(256) void k_hist(const int* __restrict__ dst,
                                              int* __restrict__ counts) {
    int e = blockIdx.x * 256 + threadIdx.x;
    if (e < NE) atomicAdd(&counts[dst[e]], 1);
}

// --- parallel scan, 3 phases ---
__global__ __launch_bounds__(512) void k_scanA(const int* __restrict__ counts,
                                               int* __restrict__ bsum) {
    __shared__ int red[512];
    int tid = threadIdx.x;
    int idx = blockIdx.x * 512 + tid;
    red[tid] = (idx < NN) ? counts[idx] : 0;
    __syncthreads();
    for (int w = 256; w > 0; w >>= 1) {
        if (tid < w) red[tid] += red[tid + w];
        __syncthreads();
    }
    if (tid == 0) bsum[blockIdx.x] = red[0];
}

__global__ __launch_bounds__(256) void k_scanB(const int* __restrict__ bsum,
                                               int* __restrict__ boff,
                                               int* __restrict__ rowptr) {
    __shared__ int sh[256];
    int tid = threadIdx.x;
    int v = (tid < SCAN_NB) ? bsum[tid] : 0;
    sh[tid] = v;
    __syncthreads();
    for (int off = 1; off < 256; off <<= 1) {
        int t = (tid >= off) ? sh[tid - off] : 0;
        __syncthreads();
        sh[tid] += t;
        __syncthreads();
    }
    if (tid < SCAN_NB) boff[tid] = sh[tid] - v;   // exclusive
    if (tid == SCAN_NB - 1) rowptr[NN] = sh[tid]; // total
}

__global__ __launch_bounds__(512) void k_scanC(const int* __restrict__ counts,
                                               const int* __restrict__ boff,
                                               int* __restrict__ rowptr,
                                               int* __restrict__ cursor) {
    __shared__ int sh[512];
    int tid = threadIdx.x;
    int idx = blockIdx.x * 512 + tid;
    int v = (idx < NN) ? counts[idx] : 0;
    sh[tid] = v;
    __syncthreads();
    for (int off = 1; off < 512; off <<= 1) {
        int t = (tid >= off) ? sh[tid - off] : 0;
        __syncthreads();
        sh[tid] += t;
        __syncthreads();
    }
    if (idx < NN) {
        int r = boff[blockIdx.x] + sh[tid] - v;   // exclusive prefix
        rowptr[idx] = r;
        cursor[idx] = r;
    }
}

__global__ __launch_bounds__(256) void k_scatter(const int* __restrict__ src,
                                                 const int* __restrict__ dst,
                                                 int* __restrict__ cursor,
                                                 int* __restrict__ epos,
                                                 int* __restrict__ psrc) {
    int e = blockIdx.x * 256 + threadIdx.x;
    if (e >= NE) return;
    int pos = atomicAdd(&cursor[dst[e]], 1);
    epos[e] = pos;
    psrc[pos] = src[e];
}

// ---------------------------------------------------------------- msg GEMM v3
#define MT 64
__global__ __launch_bounds__(256) void k_msg(
    const float* __restrict__ ea, const float* __restrict__ W,
    const float* __restrict__ bias, const int* __restrict__ epos,
    float* __restrict__ msg)
{
    __shared__ __align__(16) float Wl[DD * DD];          // 16 KB
    __shared__ __align__(16) float bl[DD];
    __shared__ __align__(16) float eaT[DD][MT + 4];      // transposed, stride 68
    int tid = threadIdx.x;
    for (int i = tid; i < DD * DD / 4; i += 256)
        ((float4*)Wl)[i] = ((const float4*)W)[i];
    if (tid < DD / 4) ((float4*)bl)[tid] = ((const float4*)bias)[tid];

    const int ntiles = NE / MT;                          // 25000
    int tx = tid & 15;           // channel group
    int ty = tid >> 4;           // edge group

    for (int tile = blockIdx.x; tile < ntiles; tile += gridDim.x) {
        __syncthreads();
#pragma unroll
        for (int i = 0; i < 4; ++i) {
            int idx = i * 256 + tid;
            int row = idx >> 4, c4 = idx & 15;
            float4 t = ((const float4*)ea)[(size_t)tile * (MT * DD / 4) + idx];
            eaT[c4 * 4 + 0][row] = t.x;
            eaT[c4 * 4 + 1][row] = t.y;
            eaT[c4 * 4 + 2][row] = t.z;
            eaT[c4 * 4 + 3][row] = t.w;
        }
        __syncthreads();

        float4 b = ((float4*)bl)[tx];
        float4 acc0 = b, acc1 = b, acc2 = b, acc3 = b;
#pragma unroll 16
        for (int k = 0; k < DD; ++k) {
            float4 w = ((float4*)Wl)[k * 16 + tx];
            float4 a = *(const float4*)&eaT[k][ty * 4];
            acc0.x = fmaf(a.x, w.x, acc0.x);
            acc0.y = fmaf(a.x, w.y, acc0.y);
            acc0.z = fmaf(a.x, w.z, acc0.z);
            acc0.w = fmaf(a.x, w.w, acc0.w);
            acc1.x = fmaf(a.y, w.x, acc1.x);
            acc1.y = fmaf(a.y, w.y, acc1.y);
            acc1.z = fmaf(a.y, w.z, acc1.z);
            acc1.w = fmaf(a.y, w.w, acc1.w);
            acc2.x = fmaf(a.z, w.x, acc2.x);
            acc2.y = fmaf(a.z, w.y, acc2.y);
            acc2.z = fmaf(a.z, w.z, acc2.z);
            acc2.w = fmaf(a.z, w.w, acc2.w);
            acc3.x = fmaf(a.w, w.x, acc3.x);
            acc3.y = fmaf(a.w, w.y, acc3.y);
            acc3.z = fmaf(a.w, w.z, acc3.z);
            acc3.w = fmaf(a.w, w.w, acc3.w);
        }
        int ebase = tile * MT + ty * 4;
        int p0 = epos[ebase + 0], p1 = epos[ebase + 1];
        int p2 = epos[ebase + 2], p3 = epos[ebase + 3];
        ((float4*)(msg + (size_t)p0 * DD))[tx] = acc0;
        ((float4*)(msg + (size_t)p1 * DD))[tx] = acc1;
        ((float4*)(msg + (size_t)p2 * DD))[tx] = acc2;
        ((float4*)(msg + (size_t)p3 * DD))[tx] = acc3;
    }
}

// ---------------------------------------------------------------- aggregate
__global__ __launch_bounds__(256) void k_agg(
    const float* __restrict__ msg, const float* __restrict__ h,
    const int* __restrict__ rowptr, const int* __restrict__ psrc,
    float* __restrict__ agg)
{
    int node = (blockIdx.x * 256 + threadIdx.x) >> 6;
    int lane = threadIdx.x & 63;
    if (node >= NN) return;
    int beg = rowptr[node], end = rowptr[node + 1];
    float acc = h[(size_t)node * DD + lane];
    int j = beg;
    for (; j + 1 < end; j += 2) {
        int s0 = psrc[j], s1 = psrc[j + 1];
        float m0 = h[(size_t)s0 * DD + lane] + msg[(size_t)j * DD + lane];
        float m1 = h[(size_t)s1 * DD + lane] + msg[(size_t)(j + 1) * DD + lane];
        acc += fmaxf(m0, 0.f) + fmaxf(m1, 0.f);
    }
    if (j < end) {
        int s = psrc[j];
        acc += fmaxf(h[(size_t)s * DD + lane] + msg[(size_t)j * DD + lane], 0.f);
    }
    agg[(size_t)node * DD + lane] = acc;
}

// ---------------------------------------------------------------- fused MLP
__global__ __launch_bounds__(256) void k_mlp(
    const float* in, const float* __restrict__ W1, const float* __restrict__ b1,
    const float* __restrict__ W2, const float* __restrict__ b2, float* out)
{
    __shared__ __align__(16) float W1l[DD * DD];
    __shared__ __align__(16) float W2l[DD * DD];
    __shared__ __align__(16) float b1l[DD];
    __shared__ __align__(16) float b2l[DD];
    int tid = threadIdx.x;
    for (int i = tid; i < DD * DD / 4; i += 256) {
        ((float4*)W1l)[i] = ((const float4*)W1)[i];
        ((float4*)W2l)[i] = ((const float4*)W2)[i];
    }
    if (tid < DD / 4) {
        ((float4*)b1l)[tid] = ((const float4*)b1)[tid];
        ((float4*)b2l)[tid] = ((const float4*)b2)[tid];
    }
    __syncthreads();

    int n = blockIdx.x * 256 + tid;
    if (n >= NN) return;

    float xr[DD];
    const float4* inrow = (const float4*)(in + (size_t)n * DD);
#pragma unroll
    for (int i = 0; i < DD / 4; ++i) {
        float4 t = inrow[i];
        xr[4*i] = t.x; xr[4*i+1] = t.y; xr[4*i+2] = t.z; xr[4*i+3] = t.w;
    }
    float z1[DD];
    for (int c4 = 0; c4 < DD / 4; ++c4) {
        float4 acc = ((float4*)b1l)[c4];
#pragma unroll
        for (int k = 0; k < DD; ++k) {
            float4 w = ((float4*)W1l)[k * (DD/4) + c4];
            acc.x = fmaf(xr[k], w.x, acc.x);
            acc.y = fmaf(xr[k], w.y, acc.y);
            acc.z = fmaf(xr[k], w.z, acc.z);
            acc.w = fmaf(xr[k], w.w, acc.w);
        }
        z1[c4*4+0] = fmaxf(acc.x, 0.f);
        z1[c4*4+1] = fmaxf(acc.y, 0.f);
        z1[c4*4+2] = fmaxf(acc.z, 0.f);
        z1[c4*4+3] = fmaxf(acc.w, 0.f);
    }
    float4* outrow = (float4*)(out + (size_t)n * DD);
    for (int c4 = 0; c4 < DD / 4; ++c4) {
        float4 acc = ((float4*)b2l)[c4];
#pragma unroll
        for (int k = 0; k < DD; ++k) {
            float4 w = ((float4*)W2l)[k * (DD/4) + c4];
            acc.x = fmaf(z1[k], w.x, acc.x);
            acc.y = fmaf(z1[k], w.y, acc.y);
            acc.z = fmaf(z1[k], w.z, acc.z);
            acc.w = fmaf(z1[k], w.w, acc.w);
        }
        float4 o;
        o.x = fmaxf(acc.x, 0.f); o.y = fmaxf(acc.y, 0.f);
        o.z = fmaxf(acc.z, 0.f); o.w = fmaxf(acc.w, 0.f);
        outrow[c4] = o;
    }
}

// ---------------------------------------------------------------- BN stats
__global__ __launch_bounds__(256) void k_stats(const float* __restrict__ z,
                                               float* __restrict__ stats) {
    int tid = threadIdx.x;
    int c = tid & 63;
    float s = 0.f, s2 = 0.f;
    for (int n = blockIdx.x * 4 + (tid >> 6); n < NN; n += 1024) {
        float v = z[(size_t)n * DD + c];
        s += v;
        s2 = fmaf(v, v, s2);
    }
    __shared__ float red[512];
    red[tid] = s; red[256 + tid] = s2;
    __syncthreads();
    if (tid < 64) {
        float a = red[tid] + red[64+tid] + red[128+tid] + red[192+tid];
        float b = red[256+tid] + red[320+tid] + red[384+tid] + red[448+tid];
        atomicAdd(&stats[c], a);
        atomicAdd(&stats[64 + c], b);
    }
}

__global__ void k_bnfinal(float* __restrict__ stats,
                          const float* __restrict__ gamma,
                          const float* __restrict__ beta) {
    int c = threadIdx.x;  // 64
    float mu  = stats[c] * (1.0f / NN);
    float var = stats[64 + c] * (1.0f / NN) - mu * mu;
    float rstd = rsqrtf(var + 1e-5f);
    float sc = gamma[c] * rstd;
    stats[c] = sc;
    stats[64 + c] = beta[c] - sc * mu;
}

// ------------------------------------------ norm + pool v2 (sorted batch)
__global__ __launch_bounds__(256) void k_norm_pool(
    const float* __restrict__ z, const float* __restrict__ stats,
    const int* __restrict__ batch, float* __restrict__ hout,
    float* __restrict__ pooled, int l)
{
    int wave = (blockIdx.x * 256 + threadIdx.x) >> 6;
    int lane = threadIdx.x & 63;
    int n0 = wave * 64;
    if (n0 >= NN) return;
    int n1 = n0 + 64; if (n1 > NN) n1 = NN;
    float sc = stats[lane], sh = stats[64 + lane];
    int gcur = batch[n0];
    float acc = 0.f;
    for (int n = n0; n < n1; ++n) {
        float h = fmaf(z[(size_t)n * DD + lane], sc, sh);
        hout[(size_t)n * DD + lane] = h;
        int g = batch[n];                    // wave-uniform broadcast
        if (g != gcur) {                     // uniform branch
            atomicAdd(&pooled[(size_t)gcur * (3 * DD) + l * DD + lane], acc);
            gcur = g; acc = 0.f;
        }
        acc += h;
    }
    atomicAdd(&pooled[(size_t)gcur * (3 * DD) + l * DD + lane], acc);
}

// ---------------------------------------------------------------- fallback
__global__ __launch_bounds__(256) void k_copy(const float* __restrict__ src,
                                              float* __restrict__ agg) {
    int total = NN * DD / 4;
    for (int i = blockIdx.x * 256 + threadIdx.x; i < total; i += gridDim.x * 256)
        ((float4*)agg)[i] = ((const float4*)src)[i];
}
__global__ __launch_bounds__(256) void k_edge(
    const float* __restrict__ ea, const float* __restrict__ h,
    const float* __restrict__ W, const float* __restrict__ bias,
    const int* __restrict__ src, const int* __restrict__ dst,
    float* __restrict__ agg)
{
    __shared__ __align__(16) float Wl[DD * DD];
    __shared__ __align__(16) float bl[DD];
    int tid = threadIdx.x;
    for (int i = tid; i < DD * DD / 4; i += 256)
        ((float4*)Wl)[i] = ((const float4*)W)[i];
    if (tid < DD / 4) ((float4*)bl)[tid] = ((const float4*)bias)[tid];
    __syncthreads();
    int e = blockIdx.x * 256 + tid;
    int s = src[e], d = dst[e];
    float av[DD];
    const float4* earow = (const float4*)(ea + (size_t)e * DD);
#pragma unroll
    for (int i = 0; i < DD / 4; ++i) {
        float4 t = earow[i];
        av[4*i] = t.x; av[4*i+1] = t.y; av[4*i+2] = t.z; av[4*i+3] = t.w;
    }
    const float4* hrow = (const float4*)(h + (size_t)s * DD);
    float* arow = agg + (size_t)d * DD;
    for (int c4 = 0; c4 < DD / 4; ++c4) {
        float4 acc = ((float4*)bl)[c4];
#pragma unroll
        for (int k = 0; k < DD; ++k) {
            float4 w = ((float4*)Wl)[k * (DD/4) + c4];
            acc.x = fmaf(av[k], w.x, acc.x);
            acc.y = fmaf(av[k], w.y, acc.y);
            acc.z = fmaf(av[k], w.z, acc.z);
            acc.w = fmaf(av[k], w.w, acc.w);
        }
        float4 hv = hrow[c4];
        atomicAdd(arow + c4*4 + 0, fmaxf(hv.x + acc.x, 0.f));
        atomicAdd(arow + c4*4 + 1, fmaxf(hv.y + acc.y, 0.f));
        atomicAdd(arow + c4*4 + 2, fmaxf(hv.z + acc.z, 0.f));
        atomicAdd(arow + c4*4 + 3, fmaxf(hv.w + acc.w, 0.f));
    }
}

// ----------------------------------------------------------------------------
extern "C" void kernel_launch(void* const* d_in, const int* in_sizes, int n_in,
                              void* d_out, int out_size, void* d_ws, size_t ws_size,
                              hipStream_t stream) {
    const float* x     = (const float*)d_in[0];
    const float* ea    = (const float*)d_in[1];
    const float* We    = (const float*)d_in[2];
    const float* be    = (const float*)d_in[3];
    const float* W1    = (const float*)d_in[4];
    const float* b1    = (const float*)d_in[5];
    const float* W2    = (const float*)d_in[6];
    const float* b2    = (const float*)d_in[7];
    const float* gamma = (const float*)d_in[8];
    const float* beta  = (const float*)d_in[9];
    const int*   eidx  = (const int*)d_in[10];
    const int*   batch = (const int*)d_in[11];
    const int* src = eidx;
    const int* dst = eidx + NE;

    float* out_pool = (float*)d_out;                  // [NG, 3*DD]
    float* out_h    = out_pool + POOLED_F;            // [NN, DD]

    const int exp_sizes[12] = {6400000, 102400000, 12288, 192, 12288, 192,
                               12288, 192, 192, 192, 3200000, 100000};
    bool ok = (n_in == 12);
    for (int i = 0; ok && i < 12; ++i) ok = (in_sizes[i] == exp_sizes[i]);
    if (!ok) {
        k_sentinel<<<1, 64, 0, stream>>>((float*)d_out, 16384.0f);
        return;
    }

    float* msg    = (float*)d_ws;                         // NE*DD f32
    float* agg    = msg + (size_t)NE * DD;                // NN*DD f32
    float* stats  = agg + (size_t)NN * DD;                // STATS_F
    int*   rowptr = (int*)(stats + STATS_F);              // NN+1
    int*   cursor = rowptr + (NN + 1);                    // NN
    int*   counts = cursor + NN;                          // NN
    int*   epos   = counts + NN;                          // NE
    int*   psrc   = epos + NE;                            // NE
    int*   bsum   = psrc + NE;                            // 256
    int*   boff   = bsum + 256;                           // 256
    size_t needed_fast = ((size_t)NE * DD + (size_t)NN * DD + STATS_F) * 4
                       + ((size_t)(NN + 1) + NN + NN + NE + NE + 512) * 4;

    k_zero<<<(POOLED_F + 255) / 256, 256, 0, stream>>>(out_pool, POOLED_F);

    if (ws_size >= needed_fast) {
        k_zero<<<(STATS_F + 255) / 256, 256, 0, stream>>>(stats, STATS_F);
        k_zeroi<<<(NN + 255) / 256, 256, 0, stream>>>(counts, NN);
        k_hist<<<NE / 256, 256, 0, stream>>>(dst, counts);
        k_scanA<<<SCAN_NB, 512, 0, stream>>>(counts, bsum);
        k_scanB<<<1, 256, 0, stream>>>(bsum, boff, rowptr);
        k_scanC<<<SCAN_NB, 512, 0, stream>>>(counts, boff, rowptr, cursor);
        k_scatter<<<NE / 256, 256, 0, stream>>>(src, dst, cursor, epos, psrc);

        for (int l = 0; l < 3; ++l) {
            const float* h = (l == 0) ? x : out_h;
            k_msg<<<2048, 256, 0, stream>>>(ea, We + l * DD * DD, be + l * DD,
                                            epos, msg);
            k_agg<<<(NN * DD + 255) / 256, 256, 0, stream>>>(msg, h, rowptr,
                                                             psrc, agg);
            k_mlp<<<(NN + 255) / 256, 256, 0, stream>>>(agg, W1 + l * DD * DD,
                                                        b1 + l * DD,
                                                        W2 + l * DD * DD,
                                                        b2 + l * DD, agg);
            k_stats<<<256, 256, 0, stream>>>(agg, stats + l * 128);
            k_bnfinal<<<1, 64, 0, stream>>>(stats + l * 128, gamma + l * DD,
                                            beta + l * DD);
            k_norm_pool<<<(NN + 255) / 256, 256, 0, stream>>>(agg, stats + l * 128,
                                                              batch, out_h,
                                                              out_pool, l);
        }
    } else {
        // fallback: round-8 proven path
        float* agg2   = (float*)d_ws;
        float* stats2 = agg2 + (size_t)NN * DD;
        if (ws_size < ((size_t)NN * DD + STATS_F) * sizeof(float)) {
            k_sentinel<<<1, 64, 0, stream>>>((float*)d_out, 32768.0f);
            return;
        }
        k_zero<<<(STATS_F + 255) / 256, 256, 0, stream>>>(stats2, STATS_F);
        for (int l = 0; l < 3; ++l) {
            const float* h = (l == 0) ? x : out_h;
            k_copy<<<2048, 256, 0, stream>>>(h, agg2);
            k_edge<<<NE / 256, 256, 0, stream>>>(ea, h, We + l * DD * DD,
                                                 be + l * DD, src, dst, agg2);
            k_mlp<<<(NN + 255) / 256, 256, 0, stream>>>(agg2, W1 + l * DD * DD,
                                                        b1 + l * DD,
                                                        W2 + l * DD * DD,
                                                        b2 + l * DD, agg2);
            k_stats<<<256, 256, 0, stream>>>(agg2, stats2 + l * 128);
            k_bnfinal<<<1, 64, 0, stream>>>(stats2 + l * 128, gamma + l * DD,
                                            beta + l * DD);
            k_norm_pool<<<(NN + 255) / 256, 256, 0, stream>>>(agg2, stats2 + l * 128,
                                                              batch, out_h,
                                                              out_pool, l);
        }
    }
}

// Round 13
// 1522.526 us; speedup vs baseline: 10.8871x; 1.0775x over previous
//
#include <hip/hip_runtime.h>
#include <hip/hip_bf16.h>

#define NN 100000
#define NE 1600000
#define DD 64
#define NG 512
#define POOLED_F (NG * 3 * DD)   // 98304
#define STATS_F  (3 * 128)
#define SCAN_NB 196              // 196 * 512 = 100352 >= NN

__global__ __launch_bounds__(256) void k_zero(float* __restrict__ p, int n) {
    int i = blockIdx.x * 256 + threadIdx.x;
    if (i < n) p[i] = 0.f;
}
__global__ __launch_bounds__(256) void k_zeroi(int* __restrict__ p, int n) {
    int i = blockIdx.x * 256 + threadIdx.x;
    if (i < n) p[i] = 0;
}
__global__ __launch_bounds__(256) void k_sentinel(float* out, float val) {
    if (threadIdx.x == 0 && blockIdx.x == 0) out[0] = val;
}

// ---------------------------------------------------------------- CSR build
__global__ __launch_bounds__(256) void k_hist(const int* __restrict__ dst,
                                              int* __restrict__ counts) {
    int e = blockIdx.x * 256 + threadIdx.x;
    if (e < NE) atomicAdd(&counts[dst[e]], 1);
}

__global__ __launch_bounds__(512) void k_scanA(const int* __restrict__ counts,
                                               int* __restrict__ bsum) {
    __shared__ int red[512];
    int tid = threadIdx.x;
    int idx = blockIdx.x * 512 + tid;
    red[tid] = (idx < NN) ? counts[idx] : 0;
    __syncthreads();
    for (int w = 256; w > 0; w >>= 1) {
        if (tid < w) red[tid] += red[tid + w];
        __syncthreads();
    }
    if (tid == 0) bsum[blockIdx.x] = red[0];
}

__global__ __launch_bounds__(256) void k_scanB(const int* __restrict__ bsum,
                                               int* __restrict__ boff,
                                               int* __restrict__ rowptr) {
    __shared__ int sh[256];
    int tid = threadIdx.x;
    int v = (tid < SCAN_NB) ? bsum[tid] : 0;
    sh[tid] = v;
    __syncthreads();
    for (int off = 1; off < 256; off <<= 1) {
        int t = (tid >= off) ? sh[tid - off] : 0;
        __syncthreads();
        sh[tid] += t;
        __syncthreads();
    }
    if (tid < SCAN_NB) boff[tid] = sh[tid] - v;   // exclusive
    if (tid == SCAN_NB - 1) rowptr[NN] = sh[tid]; // total
}

__global__ __launch_bounds__(512) void k_scanC(const int* __restrict__ counts,
                                               const int* __restrict__ boff,
                                               int* __restrict__ rowptr,
                                               int* __restrict__ cursor) {
    __shared__ int sh[512];
    int tid = threadIdx.x;
    int idx = blockIdx.x * 512 + tid;
    int v = (idx < NN) ? counts[idx] : 0;
    sh[tid] = v;
    __syncthreads();
    for (int off = 1; off < 512; off <<= 1) {
        int t = (tid >= off) ? sh[tid - off] : 0;
        __syncthreads();
        sh[tid] += t;
        __syncthreads();
    }
    if (idx < NN) {
        int r = boff[blockIdx.x] + sh[tid] - v;
        rowptr[idx] = r;
        cursor[idx] = r;
    }
}

__global__ __launch_bounds__(256) void k_scatter(const int* __restrict__ src,
                                                 const int* __restrict__ dst,
                                                 int* __restrict__ cursor,
                                                 int* __restrict__ epos,
                                                 int* __restrict__ psrc) {
    int e = blockIdx.x * 256 + threadIdx.x;
    if (e >= NE) return;
    int pos = atomicAdd(&cursor[dst[e]], 1);
    epos[e] = pos;
    psrc[pos] = src[e];
}

// ---------------------------------------------------------------- msg GEMM v4
// Tile 128 edges x 64 ch; 256 threads as 16(ty: 8 edges) x 16(tx: 4 ch).
// eaT transposed with XOR swizzle col = row ^ ((k>>3)<<2): staging writes 2-way
// (free), reads broadcast-clean. Per k: 3 ds_read_b128 -> 32 FMA (1.5 B/FLOP).
#define MT2 128
__global__ __launch_bounds__(256) void k_msg(
    const float* __restrict__ ea, const float* __restrict__ W,
    const float* __restrict__ bias, const int* __restrict__ epos,
    float* __restrict__ msg)
{
    __shared__ __align__(16) float Wl[DD * DD];       // 16 KB
    __shared__ __align__(16) float bl[DD];
    __shared__ __align__(16) float eaT[DD][MT2];      // 32 KB, swizzled cols
    int tid = threadIdx.x;
    for (int i = tid; i < DD * DD / 4; i += 256)
        ((float4*)Wl)[i] = ((const float4*)W)[i];
    if (tid < DD / 4) ((float4*)bl)[tid] = ((const float4*)bias)[tid];

    const int ntiles = NE / MT2;                      // 12500
    int tx = tid & 15;            // channel group (4 ch)
    int ty = tid >> 4;            // edge group (8 edges)
    int C = ty * 8;

    for (int tile = blockIdx.x; tile < ntiles; tile += gridDim.x) {
        __syncthreads();
#pragma unroll
        for (int i = 0; i < 8; ++i) {
            int idx = i * 256 + tid;
            int row = idx >> 4, c4 = idx & 15;
            float4 t = ((const float4*)ea)[(size_t)tile * (MT2 * DD / 4) + idx];
            int col = row ^ ((c4 >> 1) << 2);   // mask(k)=((k>>3)&7)<<2, k=4c4+j
            eaT[c4 * 4 + 0][col] = t.x;
            eaT[c4 * 4 + 1][col] = t.y;
            eaT[c4 * 4 + 2][col] = t.z;
            eaT[c4 * 4 + 3][col] = t.w;
        }
        __syncthreads();

        float4 b = ((float4*)bl)[tx];
        float4 acc[8];
#pragma unroll
        for (int r = 0; r < 8; ++r) acc[r] = b;

#pragma unroll 8
        for (int k = 0; k < DD; ++k) {
            float4 w = ((float4*)Wl)[k * 16 + tx];
            int mask = ((k >> 3) & 7) << 2;
            float4 a0 = *(const float4*)&eaT[k][C ^ mask];
            float4 a1 = *(const float4*)&eaT[k][(C + 4) ^ mask];
            float a[8] = {a0.x, a0.y, a0.z, a0.w, a1.x, a1.y, a1.z, a1.w};
#pragma unroll
            for (int r = 0; r < 8; ++r) {
                acc[r].x = fmaf(a[r], w.x, acc[r].x);
                acc[r].y = fmaf(a[r], w.y, acc[r].y);
                acc[r].z = fmaf(a[r], w.z, acc[r].z);
                acc[r].w = fmaf(a[r], w.w, acc[r].w);
            }
        }
        int ebase = tile * MT2 + C;
#pragma unroll
        for (int r = 0; r < 8; ++r) {
            int p = epos[ebase + r];
            ((float4*)(msg + (size_t)p * DD))[tx] = acc[r];
        }
    }
}

// ---------------------------------------------------------------- aggregate
// one wave per node; lane = channel; msg sequential (CSR order); unroll 4
__global__ __launch_bounds__(256) void k_agg(
    const float* __restrict__ msg, const float* __restrict__ h,
    const int* __restrict__ rowptr, const int* __restrict__ psrc,
    float* __restrict__ agg)
{
    int node = (blockIdx.x * 256 + threadIdx.x) >> 6;
    int lane = threadIdx.x & 63;
    if (node >= NN) return;
    int beg = rowptr[node], end = rowptr[node + 1];
    float acc = h[(size_t)node * DD + lane];
    int j = beg;
    for (; j + 3 < end; j += 4) {
        int s0 = psrc[j], s1 = psrc[j + 1], s2 = psrc[j + 2], s3 = psrc[j + 3];
        float m0 = h[(size_t)s0 * DD + lane] + msg[(size_t)j * DD + lane];
        float m1 = h[(size_t)s1 * DD + lane] + msg[(size_t)(j + 1) * DD + lane];
        float m2 = h[(size_t)s2 * DD + lane] + msg[(size_t)(j + 2) * DD + lane];
        float m3 = h[(size_t)s3 * DD + lane] + msg[(size_t)(j + 3) * DD + lane];
        acc += fmaxf(m0, 0.f) + fmaxf(m1, 0.f) + fmaxf(m2, 0.f) + fmaxf(m3, 0.f);
    }
    for (; j < end; ++j) {
        int s = psrc[j];
        acc += fmaxf(h[(size_t)s * DD + lane] + msg[(size_t)j * DD + lane], 0.f);
    }
    agg[(size_t)node * DD + lane] = acc;
}

// ---------------------------------------------------------------- fused MLP
__global__ __launch_bounds__(256) void k_mlp(
    const float* in, const float* __restrict__ W1, const float* __restrict__ b1,
    const float* __restrict__ W2, const float* __restrict__ b2, float* out)
{
    __shared__ __align__(16) float W1l[DD * DD];
    __shared__ __align__(16) float W2l[DD * DD];
    __shared__ __align__(16) float b1l[DD];
    __shared__ __align__(16) float b2l[DD];
    int tid = threadIdx.x;
    for (int i = tid; i < DD * DD / 4; i += 256) {
        ((float4*)W1l)[i] = ((const float4*)W1)[i];
        ((float4*)W2l)[i] = ((const float4*)W2)[i];
    }
    if (tid < DD / 4) {
        ((float4*)b1l)[tid] = ((const float4*)b1)[tid];
        ((float4*)b2l)[tid] = ((const float4*)b2)[tid];
    }
    __syncthreads();

    int n = blockIdx.x * 256 + tid;
    if (n >= NN) return;

    float xr[DD];
    const float4* inrow = (const float4*)(in + (size_t)n * DD);
#pragma unroll
    for (int i = 0; i < DD / 4; ++i) {
        float4 t = inrow[i];
        xr[4*i] = t.x; xr[4*i+1] = t.y; xr[4*i+2] = t.z; xr[4*i+3] = t.w;
    }
    float z1[DD];
    for (int c4 = 0; c4 < DD / 4; ++c4) {
        float4 acc = ((float4*)b1l)[c4];
#pragma unroll
        for (int k = 0; k < DD; ++k) {
            float4 w = ((float4*)W1l)[k * (DD/4) + c4];
            acc.x = fmaf(xr[k], w.x, acc.x);
            acc.y = fmaf(xr[k], w.y, acc.y);
            acc.z = fmaf(xr[k], w.z, acc.z);
            acc.w = fmaf(xr[k], w.w, acc.w);
        }
        z1[c4*4+0] = fmaxf(acc.x, 0.f);
        z1[c4*4+1] = fmaxf(acc.y, 0.f);
        z1[c4*4+2] = fmaxf(acc.z, 0.f);
        z1[c4*4+3] = fmaxf(acc.w, 0.f);
    }
    float4* outrow = (float4*)(out + (size_t)n * DD);
    for (int c4 = 0; c4 < DD / 4; ++c4) {
        float4 acc = ((float4*)b2l)[c4];
#pragma unroll
        for (int k = 0; k < DD; ++k) {
            float4 w = ((float4*)W2l)[k * (DD/4) + c4];
            acc.x = fmaf(z1[k], w.x, acc.x);
            acc.y = fmaf(z1[k], w.y, acc.y);
            acc.z = fmaf(z1[k], w.z, acc.z);
            acc.w = fmaf(z1[k], w.w, acc.w);
        }
        float4 o;
        o.x = fmaxf(acc.x, 0.f); o.y = fmaxf(acc.y, 0.f);
        o.z = fmaxf(acc.z, 0.f); o.w = fmaxf(acc.w, 0.f);
        outrow[c4] = o;
    }
}

// ---------------------------------------------------------------- BN stats
__global__ __launch_bounds__(256) void k_stats(const float* __restrict__ z,
                                               float* __restrict__ stats) {
    int tid = threadIdx.x;
    int c = tid & 63;
    float s = 0.f, s2 = 0.f;
    for (int n = blockIdx.x * 4 + (tid >> 6); n < NN; n += 1024) {
        float v = z[(size_t)n * DD + c];
        s += v;
        s2 = fmaf(v, v, s2);
    }
    __shared__ float red[512];
    red[tid] = s; red[256 + tid] = s2;
    __syncthreads();
    if (tid < 64) {
        float a = red[tid] + red[64+tid] + red[128+tid] + red[192+tid];
        float b = red[256+tid] + red[320+tid] + red[384+tid] + red[448+tid];
        atomicAdd(&stats[c], a);
        atomicAdd(&stats[64 + c], b);
    }
}

__global__ void k_bnfinal(float* __restrict__ stats,
                          const float* __restrict__ gamma,
                          const float* __restrict__ beta) {
    int c = threadIdx.x;  // 64
    float mu  = stats[c] * (1.0f / NN);
    float var = stats[64 + c] * (1.0f / NN) - mu * mu;
    float rstd = rsqrtf(var + 1e-5f);
    float sc = gamma[c] * rstd;
    stats[c] = sc;
    stats[64 + c] = beta[c] - sc * mu;
}

// ------------------------------------------ norm + pool (sorted batch)
__global__ __launch_bounds__(256) void k_norm_pool(
    const float* __restrict__ z, const float* __restrict__ stats,
    const int* __restrict__ batch, float* __restrict__ hout,
    float* __restrict__ pooled, int l)
{
    int wave = (blockIdx.x * 256 + threadIdx.x) >> 6;
    int lane = threadIdx.x & 63;
    int n0 = wave * 64;
    if (n0 >= NN) return;
    int n1 = n0 + 64; if (n1 > NN) n1 = NN;
    float sc = stats[lane], sh = stats[64 + lane];
    int gcur = batch[n0];
    float acc = 0.f;
    for (int n = n0; n < n1; ++n) {
        float h = fmaf(z[(size_t)n * DD + lane], sc, sh);
        hout[(size_t)n * DD + lane] = h;
        int g = batch[n];
        if (g != gcur) {
            atomicAdd(&pooled[(size_t)gcur * (3 * DD) + l * DD + lane], acc);
            gcur = g; acc = 0.f;
        }
        acc += h;
    }
    atomicAdd(&pooled[(size_t)gcur * (3 * DD) + l * DD + lane], acc);
}

// ---------------------------------------------------------------- fallback
__global__ __launch_bounds__(256) void k_copy(const float* __restrict__ src,
                                              float* __restrict__ agg) {
    int total = NN * DD / 4;
    for (int i = blockIdx.x * 256 + threadIdx.x; i < total; i += gridDim.x * 256)
        ((float4*)agg)[i] = ((const float4*)src)[i];
}
__global__ __launch_bounds__(256) void k_edge(
    const float* __restrict__ ea, const float* __restrict__ h,
    const float* __restrict__ W, const float* __restrict__ bias,
    const int* __restrict__ src, const int* __restrict__ dst,
    float* __restrict__ agg)
{
    __shared__ __align__(16) float Wl[DD * DD];
    __shared__ __align__(16) float bl[DD];
    int tid = threadIdx.x;
    for (int i = tid; i < DD * DD / 4; i += 256)
        ((float4*)Wl)[i] = ((const float4*)W)[i];
    if (tid < DD / 4) ((float4*)bl)[tid] = ((const float4*)bias)[tid];
    __syncthreads();
    int e = blockIdx.x * 256 + tid;
    int s = src[e], d = dst[e];
    float av[DD];
    const float4* earow = (const float4*)(ea + (size_t)e * DD);
#pragma unroll
    for (int i = 0; i < DD / 4; ++i) {
        float4 t = earow[i];
        av[4*i] = t.x; av[4*i+1] = t.y; av[4*i+2] = t.z; av[4*i+3] = t.w;
    }
    const float4* hrow = (const float4*)(h + (size_t)s * DD);
    float* arow = agg + (size_t)d * DD;
    for (int c4 = 0; c4 < DD / 4; ++c4) {
        float4 acc = ((float4*)bl)[c4];
#pragma unroll
        for (int k = 0; k < DD; ++k) {
            float4 w = ((float4*)Wl)[k * (DD/4) + c4];
            acc.x = fmaf(av[k], w.x, acc.x);
            acc.y = fmaf(av[k], w.y, acc.y);
            acc.z = fmaf(av[k], w.z, acc.z);
            acc.w = fmaf(av[k], w.w, acc.w);
        }
        float4 hv = hrow[c4];
        atomicAdd(arow + c4*4 + 0, fmaxf(hv.x + acc.x, 0.f));
        atomicAdd(arow + c4*4 + 1, fmaxf(hv.y + acc.y, 0.f));
        atomicAdd(arow + c4*4 + 2, fmaxf(hv.z + acc.z, 0.f));
        atomicAdd(arow + c4*4 + 3, fmaxf(hv.w + acc.w, 0.f));
    }
}

// ----------------------------------------------------------------------------
extern "C" void kernel_launch(void* const* d_in, const int* in_sizes, int n_in,
                              void* d_out, int out_size, void* d_ws, size_t ws_size,
                              hipStream_t stream) {
    const float* x     = (const float*)d_in[0];
    const float* ea    = (const float*)d_in[1];
    const float* We    = (const float*)d_in[2];
    const float* be    = (const float*)d_in[3];
    const float* W1    = (const float*)d_in[4];
    const float* b1    = (const float*)d_in[5];
    const float* W2    = (const float*)d_in[6];
    const float* b2    = (const float*)d_in[7];
    const float* gamma = (const float*)d_in[8];
    const float* beta  = (const float*)d_in[9];
    const int*   eidx  = (const int*)d_in[10];
    const int*   batch = (const int*)d_in[11];
    const int* src = eidx;
    const int* dst = eidx + NE;

    float* out_pool = (float*)d_out;                  // [NG, 3*DD]
    float* out_h    = out_pool + POOLED_F;            // [NN, DD]

    const int exp_sizes[12] = {6400000, 102400000, 12288, 192, 12288, 192,
                               12288, 192, 192, 192, 3200000, 100000};
    bool ok = (n_in == 12);
    for (int i = 0; ok && i < 12; ++i) ok = (in_sizes[i] == exp_sizes[i]);
    if (!ok) {
        k_sentinel<<<1, 64, 0, stream>>>((float*)d_out, 16384.0f);
        return;
    }

    float* msg    = (float*)d_ws;                         // NE*DD f32
    float* agg    = msg + (size_t)NE * DD;                // NN*DD f32
    float* stats  = agg + (size_t)NN * DD;                // STATS_F
    int*   rowptr = (int*)(stats + STATS_F);              // NN+1
    int*   cursor = rowptr + (NN + 1);                    // NN
    int*   counts = cursor + NN;                          // NN
    int*   epos   = counts + NN;                          // NE
    int*   psrc   = epos + NE;                            // NE
    int*   bsum   = psrc + NE;                            // 256
    int*   boff   = bsum + 256;                           // 256
    size_t needed_fast = ((size_t)NE * DD + (size_t)NN * DD + STATS_F) * 4
                       + ((size_t)(NN + 1) + NN + NN + NE + NE + 512) * 4;

    k_zero<<<(POOLED_F + 255) / 256, 256, 0, stream>>>(out_pool, POOLED_F);

    if (ws_size >= needed_fast) {
        k_zero<<<(STATS_F + 255) / 256, 256, 0, stream>>>(stats, STATS_F);
        k_zeroi<<<(NN + 255) / 256, 256, 0, stream>>>(counts, NN);
        k_hist<<<NE / 256, 256, 0, stream>>>(dst, counts);
        k_scanA<<<SCAN_NB, 512, 0, stream>>>(counts, bsum);
        k_scanB<<<1, 256, 0, stream>>>(bsum, boff, rowptr);
        k_scanC<<<SCAN_NB, 512, 0, stream>>>(counts, boff, rowptr, cursor);
        k_scatter<<<NE / 256, 256, 0, stream>>>(src, dst, cursor, epos, psrc);

        for (int l = 0; l < 3; ++l) {
            const float* h = (l == 0) ? x : out_h;
            k_msg<<<2048, 256, 0, stream>>>(ea, We + l * DD * DD, be + l * DD,
                                            epos, msg);
            k_agg<<<(NN * DD + 255) / 256, 256, 0, stream>>>(msg, h, rowptr,
                                                             psrc, agg);
            k_mlp<<<(NN + 255) / 256, 256, 0, stream>>>(agg, W1 + l * DD * DD,
                                                        b1 + l * DD,
                                                        W2 + l * DD * DD,
                                                        b2 + l * DD, agg);
            k_stats<<<256, 256, 0, stream>>>(agg, stats + l * 128);
            k_bnfinal<<<1, 64, 0, stream>>>(stats + l * 128, gamma + l * DD,
                                            beta + l * DD);
            k_norm_pool<<<(NN + 255) / 256, 256, 0, stream>>>(agg, stats + l * 128,
                                                              batch, out_h,
                                                              out_pool, l);
        }
    } else {
        // fallback: round-8 proven path
        float* agg2   = (float*)d_ws;
        float* stats2 = agg2 + (size_t)NN * DD;
        if (ws_size < ((size_t)NN * DD + STATS_F) * sizeof(float)) {
            k_sentinel<<<1, 64, 0, stream>>>((float*)d_out, 32768.0f);
            return;
        }
        k_zero<<<(STATS_F + 255) / 256, 256, 0, stream>>>(stats2, STATS_F);
        for (int l = 0; l < 3; ++l) {
            const float* h = (l == 0) ? x : out_h;
            k_copy<<<2048, 256, 0, stream>>>(h, agg2);
            k_edge<<<NE / 256, 256, 0, stream>>>(ea, h, We + l * DD * DD,
                                                 be + l * DD, src, dst, agg2);
            k_mlp<<<(NN + 255) / 256, 256, 0, stream>>>(agg2, W1 + l * DD * DD,
                                                        b1 + l * DD,
                                                        W2 + l * DD * DD,
                                                        b2 + l * DD, agg2);
            k_stats<<<256, 256, 0, stream>>>(agg2, stats2 + l * 128);
            k_bnfinal<<<1, 64, 0, stream>>>(stats2 + l * 128, gamma + l * DD,
                                            beta + l * DD);
            k_norm_pool<<<(NN + 255) / 256, 256, 0, stream>>>(agg2, stats2 + l * 128,
                                                              batch, out_h,
                                                              out_pool, l);
        }
    }
}

// Round 14
// 1437.512 us; speedup vs baseline: 11.5309x; 1.0591x over previous
//
#include <hip/hip_runtime.h>
#include <hip/hip_bf16.h>

#define NN 100000
#define NE 1600000
#define DD 64
#define NG 512
#define POOLED_F (NG * 3 * DD)   // 98304
#define STATS_F  (3 * 128)
#define SCAN_NB 196              // 196 * 512 = 100352 >= NN
#define FT 128                   // fused-msg tile (edges)

__global__ __launch_bounds__(256) void k_zero(float* __restrict__ p, int n) {
    int i = blockIdx.x * 256 + threadIdx.x;
    if (i < n) p[i] = 0.f;
}
__global__ __launch_bounds__(256) void k_zeroi(int* __restrict__ p, int n) {
    int i = blockIdx.x * 256 + threadIdx.x;
    if (i < n) p[i] = 0;
}
__global__ __launch_bounds__(256) void k_sentinel(float* out, float val) {
    if (threadIdx.x == 0 && blockIdx.x == 0) out[0] = val;
}

// ---------------------------------------------------------------- CSR build
__global__ __launch_bounds__(256) void k_hist(const int* __restrict__ dst,
                                              int* __restrict__ counts) {
    int e = blockIdx.x * 256 + threadIdx.x;
    if (e < NE) atomicAdd(&counts[dst[e]], 1);
}

__global__ __launch_bounds__(512) void k_scanA(const int* __restrict__ counts,
                                               int* __restrict__ bsum) {
    __shared__ int red[512];
    int tid = threadIdx.x;
    int idx = blockIdx.x * 512 + tid;
    red[tid] = (idx < NN) ? counts[idx] : 0;
    __syncthreads();
    for (int w = 256; w > 0; w >>= 1) {
        if (tid < w) red[tid] += red[tid + w];
        __syncthreads();
    }
    if (tid == 0) bsum[blockIdx.x] = red[0];
}

__global__ __launch_bounds__(256) void k_scanB(const int* __restrict__ bsum,
                                               int* __restrict__ boff,
                                               int* __restrict__ rowptr) {
    __shared__ int sh[256];
    int tid = threadIdx.x;
    int v = (tid < SCAN_NB) ? bsum[tid] : 0;
    sh[tid] = v;
    __syncthreads();
    for (int off = 1; off < 256; off <<= 1) {
        int t = (tid >= off) ? sh[tid - off] : 0;
        __syncthreads();
        sh[tid] += t;
        __syncthreads();
    }
    if (tid < SCAN_NB) boff[tid] = sh[tid] - v;   // exclusive
    if (tid == SCAN_NB - 1) rowptr[NN] = sh[tid]; // total
}

__global__ __launch_bounds__(512) void k_scanC(const int* __restrict__ counts,
                                               const int* __restrict__ boff,
                                               int* __restrict__ rowptr,
                                               int* __restrict__ cursor) {
    __shared__ int sh[512];
    int tid = threadIdx.x;
    int idx = blockIdx.x * 512 + tid;
    int v = (idx < NN) ? counts[idx] : 0;
    sh[tid] = v;
    __syncthreads();
    for (int off = 1; off < 512; off <<= 1) {
        int t = (tid >= off) ? sh[tid - off] : 0;
        __syncthreads();
        sh[tid] += t;
        __syncthreads();
    }
    if (idx < NN) {
        int r = boff[blockIdx.x] + sh[tid] - v;
        rowptr[idx] = r;
        cursor[idx] = r;
    }
}

__global__ __launch_bounds__(256) void k_scatter(const int* __restrict__ src,
                                                 const int* __restrict__ dst,
                                                 int* __restrict__ cursor,
                                                 int* __restrict__ epos,
                                                 int* __restrict__ psrc) {
    int e = blockIdx.x * 256 + threadIdx.x;
    if (e >= NE) return;
    int pos = atomicAdd(&cursor[dst[e]], 1);
    epos[e] = pos;
    psrc[pos] = src[e];
}

// --------------------------------------------------- fused 3-layer msg GEMM
// msg[l][epos[e]] = ea[e] @ We[l] + be[l] for l=0..2, one pass over ea.
// Tile FT=128 edges x 64 ch; 256 thr as 16(ty:8 edges) x 16(tx:4 ch);
// eaT staged in two 32-k phases (16KB) with XOR swizzle; W x3 resident (48KB).
// Per k: 2 a-b128 + 3 w-b128 feed 96 FMA.
__global__ __launch_bounds__(256) void k_fmsg(
    const float* __restrict__ ea, const float* __restrict__ We,
    const float* __restrict__ be, const int* __restrict__ epos,
    float* __restrict__ msg)
{
    __shared__ __align__(16) float Wl[3][DD * DD];    // 48 KB
    __shared__ __align__(16) float bl[3][DD];
    __shared__ __align__(16) float eaT[32][FT];       // 16 KB, swizzled
    int tid = threadIdx.x;
#pragma unroll
    for (int l = 0; l < 3; ++l) {
        for (int i = tid; i < DD * DD / 4; i += 256)
            ((float4*)Wl[l])[i] = ((const float4*)(We + l * DD * DD))[i];
        if (tid < DD / 4)
            ((float4*)bl[l])[tid] = ((const float4*)(be + l * DD))[tid];
    }

    const int ntiles = NE / FT;                       // 12500
    int tx = tid & 15, ty = tid >> 4;
    int C = ty * 8;

    for (int tile = blockIdx.x; tile < ntiles; tile += gridDim.x) {
        float4 acc[3][8];
        // ---------- phase 0: kk = 0..31 (global k 0..31)
        __syncthreads();   // protect eaT from previous tile (and initial Wl)
#pragma unroll
        for (int i = 0; i < 4; ++i) {
            int idx = i * 256 + tid;
            int row = idx >> 3, c4 = idx & 7;
            float4 t = ((const float4*)ea)[((size_t)tile * FT + row) * 16 + c4];
#pragma unroll
            for (int j = 0; j < 4; ++j) {
                int kk = c4 * 4 + j;
                int col = row ^ (((kk >> 3) & 3) << 2);
                eaT[kk][col] = (&t.x)[j];
            }
        }
        __syncthreads();
#pragma unroll
        for (int l = 0; l < 3; ++l) {
            float4 b = ((float4*)bl[l])[tx];
#pragma unroll
            for (int r = 0; r < 8; ++r) acc[l][r] = b;
        }
#pragma unroll 8
        for (int kk = 0; kk < 32; ++kk) {
            int k = kk;
            float4 w0 = ((float4*)Wl[0])[k * 16 + tx];
            float4 w1 = ((float4*)Wl[1])[k * 16 + tx];
            float4 w2 = ((float4*)Wl[2])[k * 16 + tx];
            int mask = ((kk >> 3) & 3) << 2;
            float4 a0 = *(const float4*)&eaT[kk][C ^ mask];
            float4 a1 = *(const float4*)&eaT[kk][(C + 4) ^ mask];
            float a[8] = {a0.x, a0.y, a0.z, a0.w, a1.x, a1.y, a1.z, a1.w};
#pragma unroll
            for (int r = 0; r < 8; ++r) {
                acc[0][r].x = fmaf(a[r], w0.x, acc[0][r].x);
                acc[0][r].y = fmaf(a[r], w0.y, acc[0][r].y);
                acc[0][r].z = fmaf(a[r], w0.z, acc[0][r].z);
                acc[0][r].w = fmaf(a[r], w0.w, acc[0][r].w);
                acc[1][r].x = fmaf(a[r], w1.x, acc[1][r].x);
                acc[1][r].y = fmaf(a[r], w1.y, acc[1][r].y);
                acc[1][r].z = fmaf(a[r], w1.z, acc[1][r].z);
                acc[1][r].w = fmaf(a[r], w1.w, acc[1][r].w);
                acc[2][r].x = fmaf(a[r], w2.x, acc[2][r].x);
                acc[2][r].y = fmaf(a[r], w2.y, acc[2][r].y);
                acc[2][r].z = fmaf(a[r], w2.z, acc[2][r].z);
                acc[2][r].w = fmaf(a[r], w2.w, acc[2][r].w);
            }
        }
        // ---------- phase 1: kk = 0..31 (global k 32..63)
        __syncthreads();
#pragma unroll
        for (int i = 0; i < 4; ++i) {
            int idx = i * 256 + tid;
            int row = idx >> 3, c4 = idx & 7;
            float4 t = ((const float4*)ea)[((size_t)tile * FT + row) * 16 + 8 + c4];
#pragma unroll
            for (int j = 0; j < 4; ++j) {
                int kk = c4 * 4 + j;
                int col = row ^ (((kk >> 3) & 3) << 2);
                eaT[kk][col] = (&t.x)[j];
            }
        }
        __syncthreads();
#pragma unroll 8
        for (int kk = 0; kk < 32; ++kk) {
            int k = 32 + kk;
            float4 w0 = ((float4*)Wl[0])[k * 16 + tx];
            float4 w1 = ((float4*)Wl[1])[k * 16 + tx];
            float4 w2 = ((float4*)Wl[2])[k * 16 + tx];
            int mask = ((kk >> 3) & 3) << 2;
            float4 a0 = *(const float4*)&eaT[kk][C ^ mask];
            float4 a1 = *(const float4*)&eaT[kk][(C + 4) ^ mask];
            float a[8] = {a0.x, a0.y, a0.z, a0.w, a1.x, a1.y, a1.z, a1.w};
#pragma unroll
            for (int r = 0; r < 8; ++r) {
                acc[0][r].x = fmaf(a[r], w0.x, acc[0][r].x);
                acc[0][r].y = fmaf(a[r], w0.y, acc[0][r].y);
                acc[0][r].z = fmaf(a[r], w0.z, acc[0][r].z);
                acc[0][r].w = fmaf(a[r], w0.w, acc[0][r].w);
                acc[1][r].x = fmaf(a[r], w1.x, acc[1][r].x);
                acc[1][r].y = fmaf(a[r], w1.y, acc[1][r].y);
                acc[1][r].z = fmaf(a[r], w1.z, acc[1][r].z);
                acc[1][r].w = fmaf(a[r], w1.w, acc[1][r].w);
                acc[2][r].x = fmaf(a[r], w2.x, acc[2][r].x);
                acc[2][r].y = fmaf(a[r], w2.y, acc[2][r].y);
                acc[2][r].z = fmaf(a[r], w2.z, acc[2][r].z);
                acc[2][r].w = fmaf(a[r], w2.w, acc[2][r].w);
            }
        }
        // ---------- write out (CSR-permuted rows, 3 layers)
        int ebase = tile * FT + C;
        int p[8];
#pragma unroll
        for (int r = 0; r < 8; ++r) p[r] = epos[ebase + r];
#pragma unroll
        for (int l = 0; l < 3; ++l) {
#pragma unroll
            for (int r = 0; r < 8; ++r) {
                ((float4*)(msg + ((size_t)l * NE + p[r]) * DD))[tx] = acc[l][r];
            }
        }
    }
}

// ---------------------------------------------------------------- aggregate
// one wave per node; lane = channel; msg sequential (CSR order); unroll 4
__global__ __launch_bounds__(256) void k_agg(
    const float* __restrict__ msg, const float* __restrict__ h,
    const int* __restrict__ rowptr, const int* __restrict__ psrc,
    float* __restrict__ agg)
{
    int node = (blockIdx.x * 256 + threadIdx.x) >> 6;
    int lane = threadIdx.x & 63;
    if (node >= NN) return;
    int beg = rowptr[node], end = rowptr[node + 1];
    float acc = h[(size_t)node * DD + lane];
    int j = beg;
    for (; j + 3 < end; j += 4) {
        int s0 = psrc[j], s1 = psrc[j + 1], s2 = psrc[j + 2], s3 = psrc[j + 3];
        float m0 = h[(size_t)s0 * DD + lane] + msg[(size_t)j * DD + lane];
        float m1 = h[(size_t)s1 * DD + lane] + msg[(size_t)(j + 1) * DD + lane];
        float m2 = h[(size_t)s2 * DD + lane] + msg[(size_t)(j + 2) * DD + lane];
        float m3 = h[(size_t)s3 * DD + lane] + msg[(size_t)(j + 3) * DD + lane];
        acc += fmaxf(m0, 0.f) + fmaxf(m1, 0.f) + fmaxf(m2, 0.f) + fmaxf(m3, 0.f);
    }
    for (; j < end; ++j) {
        int s = psrc[j];
        acc += fmaxf(h[(size_t)s * DD + lane] + msg[(size_t)j * DD + lane], 0.f);
    }
    agg[(size_t)node * DD + lane] = acc;
}

// ---------------------------------------------------------------- fused MLP
__global__ __launch_bounds__(256) void k_mlp(
    const float* in, const float* __restrict__ W1, const float* __restrict__ b1,
    const float* __restrict__ W2, const float* __restrict__ b2, float* out)
{
    __shared__ __align__(16) float W1l[DD * DD];
    __shared__ __align__(16) float W2l[DD * DD];
    __shared__ __align__(16) float b1l[DD];
    __shared__ __align__(16) float b2l[DD];
    int tid = threadIdx.x;
    for (int i = tid; i < DD * DD / 4; i += 256) {
        ((float4*)W1l)[i] = ((const float4*)W1)[i];
        ((float4*)W2l)[i] = ((const float4*)W2)[i];
    }
    if (tid < DD / 4) {
        ((float4*)b1l)[tid] = ((const float4*)b1)[tid];
        ((float4*)b2l)[tid] = ((const float4*)b2)[tid];
    }
    __syncthreads();

    int n = blockIdx.x * 256 + tid;
    if (n >= NN) return;

    float xr[DD];
    const float4* inrow = (const float4*)(in + (size_t)n * DD);
#pragma unroll
    for (int i = 0; i < DD / 4; ++i) {
        float4 t = inrow[i];
        xr[4*i] = t.x; xr[4*i+1] = t.y; xr[4*i+2] = t.z; xr[4*i+3] = t.w;
    }
    float z1[DD];
    for (int c4 = 0; c4 < DD / 4; ++c4) {
        float4 acc = ((float4*)b1l)[c4];
#pragma unroll
        for (int k = 0; k < DD; ++k) {
            float4 w = ((float4*)W1l)[k * (DD/4) + c4];
            acc.x = fmaf(xr[k], w.x, acc.x);
            acc.y = fmaf(xr[k], w.y, acc.y);
            acc.z = fmaf(xr[k], w.z, acc.z);
            acc.w = fmaf(xr[k], w.w, acc.w);
        }
        z1[c4*4+0] = fmaxf(acc.x, 0.f);
        z1[c4*4+1] = fmaxf(acc.y, 0.f);
        z1[c4*4+2] = fmaxf(acc.z, 0.f);
        z1[c4*4+3] = fmaxf(acc.w, 0.f);
    }
    float4* outrow = (float4*)(out + (size_t)n * DD);
    for (int c4 = 0; c4 < DD / 4; ++c4) {
        float4 acc = ((float4*)b2l)[c4];
#pragma unroll
        for (int k = 0; k < DD; ++k) {
            float4 w = ((float4*)W2l)[k * (DD/4) + c4];
            acc.x = fmaf(z1[k], w.x, acc.x);
            acc.y = fmaf(z1[k], w.y, acc.y);
            acc.z = fmaf(z1[k], w.z, acc.z);
            acc.w = fmaf(z1[k], w.w, acc.w);
        }
        float4 o;
        o.x = fmaxf(acc.x, 0.f); o.y = fmaxf(acc.y, 0.f);
        o.z = fmaxf(acc.z, 0.f); o.w = fmaxf(acc.w, 0.f);
        outrow[c4] = o;
    }
}

// ---------------------------------------------------------------- BN stats
__global__ __launch_bounds__(256) void k_stats(const float* __restrict__ z,
                                               float* __restrict__ stats) {
    int tid = threadIdx.x;
    int c = tid & 63;
    float s = 0.f, s2 = 0.f;
    for (int n = blockIdx.x * 4 + (tid >> 6); n < NN; n += 1024) {
        float v = z[(size_t)n * DD + c];
        s += v;
        s2 = fmaf(v, v, s2);
    }
    __shared__ float red[512];
    red[tid] = s; red[256 + tid] = s2;
    __syncthreads();
    if (tid < 64) {
        float a = red[tid] + red[64+tid] + red[128+tid] + red[192+tid];
        float b = red[256+tid] + red[320+tid] + red[384+tid] + red[448+tid];
        atomicAdd(&stats[c], a);
        atomicAdd(&stats[64 + c], b);
    }
}

__global__ void k_bnfinal(float* __restrict__ stats,
                          const float* __restrict__ gamma,
                          const float* __restrict__ beta) {
    int c = threadIdx.x;  // 64
    float mu  = stats[c] * (1.0f / NN);
    float var = stats[64 + c] * (1.0f / NN) - mu * mu;
    float rstd = rsqrtf(var + 1e-5f);
    float sc = gamma[c] * rstd;
    stats[c] = sc;
    stats[64 + c] = beta[c] - sc * mu;
}

// ------------------------------------------ norm + pool (sorted batch)
__global__ __launch_bounds__(256) void k_norm_pool(
    const float* __restrict__ z, const float* __restrict__ stats,
    const int* __restrict__ batch, float* __restrict__ hout,
    float* __restrict__ pooled, int l)
{
    int wave = (blockIdx.x * 256 + threadIdx.x) >> 6;
    int lane = threadIdx.x & 63;
    int n0 = wave * 64;
    if (n0 >= NN) return;
    int n1 = n0 + 64; if (n1 > NN) n1 = NN;
    float sc = stats[lane], sh = stats[64 + lane];
    int gcur = batch[n0];
    float acc = 0.f;
    for (int n = n0; n < n1; ++n) {
        float h = fmaf(z[(size_t)n * DD + lane], sc, sh);
        hout[(size_t)n * DD + lane] = h;
        int g = batch[n];
        if (g != gcur) {
            atomicAdd(&pooled[(size_t)gcur * (3 * DD) + l * DD + lane], acc);
            gcur = g; acc = 0.f;
        }
        acc += h;
    }
    atomicAdd(&pooled[(size_t)gcur * (3 * DD) + l * DD + lane], acc);
}

// ---------------------------------------------------------------- fallback
__global__ __launch_bounds__(256) void k_copy(const float* __restrict__ src,
                                              float* __restrict__ agg) {
    int total = NN * DD / 4;
    for (int i = blockIdx.x * 256 + threadIdx.x; i < total; i += gridDim.x * 256)
        ((float4*)agg)[i] = ((const float4*)src)[i];
}
__global__ __launch_bounds__(256) void k_edge(
    const float* __restrict__ ea, const float* __restrict__ h,
    const float* __restrict__ W, const float* __restrict__ bias,
    const int* __restrict__ src, const int* __restrict__ dst,
    float* __restrict__ agg)
{
    __shared__ __align__(16) float Wl[DD * DD];
    __shared__ __align__(16) float bl[DD];
    int tid = threadIdx.x;
    for (int i = tid; i < DD * DD / 4; i += 256)
        ((float4*)Wl)[i] = ((const float4*)W)[i];
    if (tid < DD / 4) ((float4*)bl)[tid] = ((const float4*)bias)[tid];
    __syncthreads();
    int e = blockIdx.x * 256 + tid;
    int s = src[e], d = dst[e];
    float av[DD];
    const float4* earow = (const float4*)(ea + (size_t)e * DD);
#pragma unroll
    for (int i = 0; i < DD / 4; ++i) {
        float4 t = earow[i];
        av[4*i] = t.x; av[4*i+1] = t.y; av[4*i+2] = t.z; av[4*i+3] = t.w;
    }
    const float4* hrow = (const float4*)(h + (size_t)s * DD);
    float* arow = agg + (size_t)d * DD;
    for (int c4 = 0; c4 < DD / 4; ++c4) {
        float4 acc = ((float4*)bl)[c4];
#pragma unroll
        for (int k = 0; k < DD; ++k) {
            float4 w = ((float4*)Wl)[k * (DD/4) + c4];
            acc.x = fmaf(av[k], w.x, acc.x);
            acc.y = fmaf(av[k], w.y, acc.y);
            acc.z = fmaf(av[k], w.z, acc.z);
            acc.w = fmaf(av[k], w.w, acc.w);
        }
        float4 hv = hrow[c4];
        atomicAdd(arow + c4*4 + 0, fmaxf(hv.x + acc.x, 0.f));
        atomicAdd(arow + c4*4 + 1, fmaxf(hv.y + acc.y, 0.f));
        atomicAdd(arow + c4*4 + 2, fmaxf(hv.z + acc.z, 0.f));
        atomicAdd(arow + c4*4 + 3, fmaxf(hv.w + acc.w, 0.f));
    }
}

// ----------------------------------------------------------------------------
extern "C" void kernel_launch(void* const* d_in, const int* in_sizes, int n_in,
                              void* d_out, int out_size, void* d_ws, size_t ws_size,
                              hipStream_t stream) {
    const float* x     = (const float*)d_in[0];
    const float* ea    = (const float*)d_in[1];
    const float* We    = (const float*)d_in[2];
    const float* be    = (const float*)d_in[3];
    const float* W1    = (const float*)d_in[4];
    const float* b1    = (const float*)d_in[5];
    const float* W2    = (const float*)d_in[6];
    const float* b2    = (const float*)d_in[7];
    const float* gamma = (const float*)d_in[8];
    const float* beta  = (const float*)d_in[9];
    const int*   eidx  = (const int*)d_in[10];
    const int*   batch = (const int*)d_in[11];
    const int* src = eidx;
    const int* dst = eidx + NE;

    float* out_pool = (float*)d_out;                  // [NG, 3*DD]
    float* out_h    = out_pool + POOLED_F;            // [NN, DD]

    const int exp_sizes[12] = {6400000, 102400000, 12288, 192, 12288, 192,
                               12288, 192, 192, 192, 3200000, 100000};
    bool ok = (n_in == 12);
    for (int i = 0; ok && i < 12; ++i) ok = (in_sizes[i] == exp_sizes[i]);
    if (!ok) {
        k_sentinel<<<1, 64, 0, stream>>>((float*)d_out, 16384.0f);
        return;
    }

    float* msg    = (float*)d_ws;                         // 3 * NE*DD f32
    float* agg    = msg + (size_t)3 * NE * DD;            // NN*DD f32
    float* stats  = agg + (size_t)NN * DD;                // STATS_F
    int*   rowptr = (int*)(stats + STATS_F);              // NN+1
    int*   cursor = rowptr + (NN + 1);                    // NN
    int*   counts = cursor + NN;                          // NN
    int*   epos   = counts + NN;                          // NE
    int*   psrc   = epos + NE;                            // NE
    int*   bsum   = psrc + NE;                            // 256
    int*   boff   = bsum + 256;                           // 256
    size_t needed_fast = ((size_t)3 * NE * DD + (size_t)NN * DD + STATS_F) * 4
                       + ((size_t)(NN + 1) + NN + NN + NE + NE + 512) * 4;

    k_zero<<<(POOLED_F + 255) / 256, 256, 0, stream>>>(out_pool, POOLED_F);

    if (ws_size >= needed_fast) {
        k_zero<<<(STATS_F + 255) / 256, 256, 0, stream>>>(stats, STATS_F);
        k_zeroi<<<(NN + 255) / 256, 256, 0, stream>>>(counts, NN);
        k_hist<<<NE / 256, 256, 0, stream>>>(dst, counts);
        k_scanA<<<SCAN_NB, 512, 0, stream>>>(counts, bsum);
        k_scanB<<<1, 256, 0, stream>>>(bsum, boff, rowptr);
        k_scanC<<<SCAN_NB, 512, 0, stream>>>(counts, boff, rowptr, cursor);
        k_scatter<<<NE / 256, 256, 0, stream>>>(src, dst, cursor, epos, psrc);

        // one fused pass computes all 3 layers' edge GEMMs
        k_fmsg<<<1024, 256, 0, stream>>>(ea, We, be, epos, msg);

        for (int l = 0; l < 3; ++l) {
            const float* h = (l == 0) ? x : out_h;
            const float* msg_l = msg + (size_t)l * NE * DD;
            k_agg<<<(NN * DD + 255) / 256, 256, 0, stream>>>(msg_l, h, rowptr,
                                                             psrc, agg);
            k_mlp<<<(NN + 255) / 256, 256, 0, stream>>>(agg, W1 + l * DD * DD,
                                                        b1 + l * DD,
                                                        W2 + l * DD * DD,
                                                        b2 + l * DD, agg);
            k_stats<<<256, 256, 0, stream>>>(agg, stats + l * 128);
            k_bnfinal<<<1, 64, 0, stream>>>(stats + l * 128, gamma + l * DD,
                                            beta + l * DD);
            k_norm_pool<<<(NN + 255) / 256, 256, 0, stream>>>(agg, stats + l * 128,
                                                              batch, out_h,
                                                              out_pool, l);
        }
    } else {
        // fallback: round-8 proven path
        float* agg2   = (float*)d_ws;
        float* stats2 = agg2 + (size_t)NN * DD;
        if (ws_size < ((size_t)NN * DD + STATS_F) * sizeof(float)) {
            k_sentinel<<<1, 64, 0, stream>>>((float*)d_out, 32768.0f);
            return;
        }
        k_zero<<<(STATS_F + 255) / 256, 256, 0, stream>>>(stats2, STATS_F);
        for (int l = 0; l < 3; ++l) {
            const float* h = (l == 0) ? x : out_h;
            k_copy<<<2048, 256, 0, stream>>>(h, agg2);
            k_edge<<<NE / 256, 256, 0, stream>>>(ea, h, We + l * DD * DD,
                                                 be + l * DD, src, dst, agg2);
            k_mlp<<<(NN + 255) / 256, 256, 0, stream>>>(agg2, W1 + l * DD * DD,
                                                        b1 + l * DD,
                                                        W2 + l * DD * DD,
                                                        b2 + l * DD, agg2);
            k_stats<<<256, 256, 0, stream>>>(agg2, stats2 + l * 128);
            k_bnfinal<<<1, 64, 0, stream>>>(stats2 + l * 128, gamma + l * DD,
                                            beta + l * DD);
            k_norm_pool<<<(NN + 255) / 256, 256, 0, stream>>>(agg2, stats2 + l * 128,
                                                              batch, out_h,
                                                              out_pool, l);
        }
    }
}

// Round 15
// 1357.951 us; speedup vs baseline: 12.2065x; 1.0586x over previous
//
#include <hip/hip_runtime.h>
#include <hip/hip_bf16.h>

#define NN 100000
#define NE 1600000
#define DD 64
#define NG 512
#define POOLED_F (NG * 3 * DD)   // 98304
#define STATS_F  (3 * 128)
#define SCAN_NB 196              // 196 * 512 = 100352 >= NN
#define FT 128                   // fused-msg tile (edges)

typedef unsigned short u16;

__device__ __forceinline__ float bf2f(u16 u) {
    return __uint_as_float(((unsigned)u) << 16);
}
__device__ __forceinline__ u16 f2bf(float f) {  // RNE
    unsigned b = __float_as_uint(f);
    return (u16)((b + 0x7FFFu + ((b >> 16) & 1u)) >> 16);
}

__global__ __launch_bounds__(256) void k_zero(float* __restrict__ p, int n) {
    int i = blockIdx.x * 256 + threadIdx.x;
    if (i < n) p[i] = 0.f;
}
__global__ __launch_bounds__(256) void k_zeroi(int* __restrict__ p, int n) {
    int i = blockIdx.x * 256 + threadIdx.x;
    if (i < n) p[i] = 0;
}
__global__ __launch_bounds__(256) void k_sentinel(float* out, float val) {
    if (threadIdx.x == 0 && blockIdx.x == 0) out[0] = val;
}

// ---------------------------------------------------------------- CSR build
__global__ __launch_bounds__(256) void k_hist(const int* __restrict__ dst,
                                              int* __restrict__ counts) {
    int e = blockIdx.x * 256 + threadIdx.x;
    if (e < NE) atomicAdd(&counts[dst[e]], 1);
}

__global__ __launch_bounds__(512) void k_scanA(const int* __restrict__ counts,
                                               int* __restrict__ bsum) {
    __shared__ int red[512];
    int tid = threadIdx.x;
    int idx = blockIdx.x * 512 + tid;
    red[tid] = (idx < NN) ? counts[idx] : 0;
    __syncthreads();
    for (int w = 256; w > 0; w >>= 1) {
        if (tid < w) red[tid] += red[tid + w];
        __syncthreads();
    }
    if (tid == 0) bsum[blockIdx.x] = red[0];
}

__global__ __launch_bounds__(256) void k_scanB(const int* __restrict__ bsum,
                                               int* __restrict__ boff,
                                               int* __restrict__ rowptr) {
    __shared__ int sh[256];
    int tid = threadIdx.x;
    int v = (tid < SCAN_NB) ? bsum[tid] : 0;
    sh[tid] = v;
    __syncthreads();
    for (int off = 1; off < 256; off <<= 1) {
        int t = (tid >= off) ? sh[tid - off] : 0;
        __syncthreads();
        sh[tid] += t;
        __syncthreads();
    }
    if (tid < SCAN_NB) boff[tid] = sh[tid] - v;   // exclusive
    if (tid == SCAN_NB - 1) rowptr[NN] = sh[tid]; // total
}

__global__ __launch_bounds__(512) void k_scanC(const int* __restrict__ counts,
                                               const int* __restrict__ boff,
                                               int* __restrict__ rowptr,
                                               int* __restrict__ cursor) {
    __shared__ int sh[512];
    int tid = threadIdx.x;
    int idx = blockIdx.x * 512 + tid;
    int v = (idx < NN) ? counts[idx] : 0;
    sh[tid] = v;
    __syncthreads();
    for (int off = 1; off < 512; off <<= 1) {
        int t = (tid >= off) ? sh[tid - off] : 0;
        __syncthreads();
        sh[tid] += t;
        __syncthreads();
    }
    if (idx < NN) {
        int r = boff[blockIdx.x] + sh[tid] - v;
        rowptr[idx] = r;
        cursor[idx] = r;
    }
}

__global__ __launch_bounds__(256) void k_scatter(const int* __restrict__ src,
                                                 const int* __restrict__ dst,
                                                 int* __restrict__ cursor,
                                                 int* __restrict__ epos,
                                                 int* __restrict__ psrc) {
    int e = blockIdx.x * 256 + threadIdx.x;
    if (e >= NE) return;
    int pos = atomicAdd(&cursor[dst[e]], 1);
    epos[e] = pos;
    psrc[pos] = src[e];
}

// --------------------------------------------------- fused 3-layer msg GEMM
// W cached in LDS as bf16 (24 KB); eaT f32 swizzled (16 KB); acc f32;
// msg written as bf16 (halves HBM round-trip). Same FMA order as r14.
__global__ __launch_bounds__(256) void k_fmsg(
    const float* __restrict__ ea, const float* __restrict__ We,
    const float* __restrict__ be, const int* __restrict__ epos,
    u16* __restrict__ msgb)
{
    __shared__ __align__(16) u16 Wb[3 * DD * DD];     // 24 KB bf16
    __shared__ __align__(16) float bl[3][DD];
    __shared__ __align__(16) float eaT[32][FT];       // 16 KB, swizzled
    int tid = threadIdx.x;
    for (int i = tid; i < 3 * DD * DD / 4; i += 256) {
        float4 t = ((const float4*)We)[i];
        ushort4 u;
        u.x = f2bf(t.x); u.y = f2bf(t.y); u.z = f2bf(t.z); u.w = f2bf(t.w);
        ((ushort4*)Wb)[i] = u;
    }
    if (tid < 3 * DD / 4)
        ((float4*)&bl[0][0])[tid] = ((const float4*)be)[tid];

    const int ntiles = NE / FT;                       // 12500
    int tx = tid & 15, ty = tid >> 4;
    int C = ty * 8;

    for (int tile = blockIdx.x; tile < ntiles; tile += gridDim.x) {
        float4 acc[3][8];
        // ---------- phase 0: k 0..31
        __syncthreads();
#pragma unroll
        for (int i = 0; i < 4; ++i) {
            int idx = i * 256 + tid;
            int row = idx >> 3, c4 = idx & 7;
            float4 t = ((const float4*)ea)[((size_t)tile * FT + row) * 16 + c4];
#pragma unroll
            for (int j = 0; j < 4; ++j) {
                int kk = c4 * 4 + j;
                int col = row ^ (((kk >> 3) & 3) << 2);
                eaT[kk][col] = (&t.x)[j];
            }
        }
        __syncthreads();
#pragma unroll
        for (int l = 0; l < 3; ++l) {
            float4 b = ((float4*)bl[l])[tx];
#pragma unroll
            for (int r = 0; r < 8; ++r) acc[l][r] = b;
        }
#pragma unroll 8
        for (int kk = 0; kk < 32; ++kk) {
            int k = kk;
            ushort4 u0 = ((const ushort4*)Wb)[0 * 1024 + k * 16 + tx];
            ushort4 u1 = ((const ushort4*)Wb)[1 * 1024 + k * 16 + tx];
            ushort4 u2 = ((const ushort4*)Wb)[2 * 1024 + k * 16 + tx];
            float4 w0 = {bf2f(u0.x), bf2f(u0.y), bf2f(u0.z), bf2f(u0.w)};
            float4 w1 = {bf2f(u1.x), bf2f(u1.y), bf2f(u1.z), bf2f(u1.w)};
            float4 w2 = {bf2f(u2.x), bf2f(u2.y), bf2f(u2.z), bf2f(u2.w)};
            int mask = ((kk >> 3) & 3) << 2;
            float4 a0 = *(const float4*)&eaT[kk][C ^ mask];
            float4 a1 = *(const float4*)&eaT[kk][(C + 4) ^ mask];
            float a[8] = {a0.x, a0.y, a0.z, a0.w, a1.x, a1.y, a1.z, a1.w};
#pragma unroll
            for (int r = 0; r < 8; ++r) {
                acc[0][r].x = fmaf(a[r], w0.x, acc[0][r].x);
                acc[0][r].y = fmaf(a[r], w0.y, acc[0][r].y);
                acc[0][r].z = fmaf(a[r], w0.z, acc[0][r].z);
                acc[0][r].w = fmaf(a[r], w0.w, acc[0][r].w);
                acc[1][r].x = fmaf(a[r], w1.x, acc[1][r].x);
                acc[1][r].y = fmaf(a[r], w1.y, acc[1][r].y);
                acc[1][r].z = fmaf(a[r], w1.z, acc[1][r].z);
                acc[1][r].w = fmaf(a[r], w1.w, acc[1][r].w);
                acc[2][r].x = fmaf(a[r], w2.x, acc[2][r].x);
                acc[2][r].y = fmaf(a[r], w2.y, acc[2][r].y);
                acc[2][r].z = fmaf(a[r], w2.z, acc[2][r].z);
                acc[2][r].w = fmaf(a[r], w2.w, acc[2][r].w);
            }
        }
        // ---------- phase 1: k 32..63
        __syncthreads();
#pragma unroll
        for (int i = 0; i < 4; ++i) {
            int idx = i * 256 + tid;
            int row = idx >> 3, c4 = idx & 7;
            float4 t = ((const float4*)ea)[((size_t)tile * FT + row) * 16 + 8 + c4];
#pragma unroll
            for (int j = 0; j < 4; ++j) {
                int kk = c4 * 4 + j;
                int col = row ^ (((kk >> 3) & 3) << 2);
                eaT[kk][col] = (&t.x)[j];
            }
        }
        __syncthreads();
#pragma unroll 8
        for (int kk = 0; kk < 32; ++kk) {
            int k = 32 + kk;
            ushort4 u0 = ((const ushort4*)Wb)[0 * 1024 + k * 16 + tx];
            ushort4 u1 = ((const ushort4*)Wb)[1 * 1024 + k * 16 + tx];
            ushort4 u2 = ((const ushort4*)Wb)[2 * 1024 + k * 16 + tx];
            float4 w0 = {bf2f(u0.x), bf2f(u0.y), bf2f(u0.z), bf2f(u0.w)};
            float4 w1 = {bf2f(u1.x), bf2f(u1.y), bf2f(u1.z), bf2f(u1.w)};
            float4 w2 = {bf2f(u2.x), bf2f(u2.y), bf2f(u2.z), bf2f(u2.w)};
            int mask = ((kk >> 3) & 3) << 2;
            float4 a0 = *(const float4*)&eaT[kk][C ^ mask];
            float4 a1 = *(const float4*)&eaT[kk][(C + 4) ^ mask];
            float a[8] = {a0.x, a0.y, a0.z, a0.w, a1.x, a1.y, a1.z, a1.w};
#pragma unroll
            for (int r = 0; r < 8; ++r) {
                acc[0][r].x = fmaf(a[r], w0.x, acc[0][r].x);
                acc[0][r].y = fmaf(a[r], w0.y, acc[0][r].y);
                acc[0][r].z = fmaf(a[r], w0.z, acc[0][r].z);
                acc[0][r].w = fmaf(a[r], w0.w, acc[0][r].w);
                acc[1][r].x = fmaf(a[r], w1.x, acc[1][r].x);
                acc[1][r].y = fmaf(a[r], w1.y, acc[1][r].y);
                acc[1][r].z = fmaf(a[r], w1.z, acc[1][r].z);
                acc[1][r].w = fmaf(a[r], w1.w, acc[1][r].w);
                acc[2][r].x = fmaf(a[r], w2.x, acc[2][r].x);
                acc[2][r].y = fmaf(a[r], w2.y, acc[2][r].y);
                acc[2][r].z = fmaf(a[r], w2.z, acc[2][r].z);
                acc[2][r].w = fmaf(a[r], w2.w, acc[2][r].w);
            }
        }
        // ---------- write out bf16 (CSR-permuted rows, 3 layers)
        int ebase = tile * FT + C;
        int p[8];
#pragma unroll
        for (int r = 0; r < 8; ++r) p[r] = epos[ebase + r];
#pragma unroll
        for (int l = 0; l < 3; ++l) {
#pragma unroll
            for (int r = 0; r < 8; ++r) {
                ushort4 o;
                o.x = f2bf(acc[l][r].x); o.y = f2bf(acc[l][r].y);
                o.z = f2bf(acc[l][r].z); o.w = f2bf(acc[l][r].w);
                ((ushort4*)(msgb + ((size_t)l * NE + p[r]) * DD))[tx] = o;
            }
        }
    }
}

// ---------------------------------------------------------------- aggregate
// one wave per node; lane = channel; msg (bf16) sequential; unroll 4
__global__ __launch_bounds__(256) void k_agg(
    const u16* __restrict__ msgb, const float* __restrict__ h,
    const int* __restrict__ rowptr, const int* __restrict__ psrc,
    float* __restrict__ agg)
{
    int node = (blockIdx.x * 256 + threadIdx.x) >> 6;
    int lane = threadIdx.x & 63;
    if (node >= NN) return;
    int beg = rowptr[node], end = rowptr[node + 1];
    float acc = h[(size_t)node * DD + lane];
    int j = beg;
    for (; j + 3 < end; j += 4) {
        int s0 = psrc[j], s1 = psrc[j + 1], s2 = psrc[j + 2], s3 = psrc[j + 3];
        float m0 = h[(size_t)s0 * DD + lane] + bf2f(msgb[(size_t)j * DD + lane]);
        float m1 = h[(size_t)s1 * DD + lane] + bf2f(msgb[(size_t)(j + 1) * DD + lane]);
        float m2 = h[(size_t)s2 * DD + lane] + bf2f(msgb[(size_t)(j + 2) * DD + lane]);
        float m3 = h[(size_t)s3 * DD + lane] + bf2f(msgb[(size_t)(j + 3) * DD + lane]);
        acc += fmaxf(m0, 0.f) + fmaxf(m1, 0.f) + fmaxf(m2, 0.f) + fmaxf(m3, 0.f);
    }
    for (; j < end; ++j) {
        int s = psrc[j];
        acc += fmaxf(h[(size_t)s * DD + lane] + bf2f(msgb[(size_t)j * DD + lane]), 0.f);
    }
    agg[(size_t)node * DD + lane] = acc;
}

// ---------------------------------------------------------------- fused MLP
__global__ __launch_bounds__(256) void k_mlp(
    const float* in, const float* __restrict__ W1, const float* __restrict__ b1,
    const float* __restrict__ W2, const float* __restrict__ b2, float* out)
{
    __shared__ __align__(16) float W1l[DD * DD];
    __shared__ __align__(16) float W2l[DD * DD];
    __shared__ __align__(16) float b1l[DD];
    __shared__ __align__(16) float b2l[DD];
    int tid = threadIdx.x;
    for (int i = tid; i < DD * DD / 4; i += 256) {
        ((float4*)W1l)[i] = ((const float4*)W1)[i];
        ((float4*)W2l)[i] = ((const float4*)W2)[i];
    }
    if (tid < DD / 4) {
        ((float4*)b1l)[tid] = ((const float4*)b1)[tid];
        ((float4*)b2l)[tid] = ((const float4*)b2)[tid];
    }
    __syncthreads();

    int n = blockIdx.x * 256 + tid;
    if (n >= NN) return;

    float xr[DD];
    const float4* inrow = (const float4*)(in + (size_t)n * DD);
#pragma unroll
    for (int i = 0; i < DD / 4; ++i) {
        float4 t = inrow[i];
        xr[4*i] = t.x; xr[4*i+1] = t.y; xr[4*i+2] = t.z; xr[4*i+3] = t.w;
    }
    float z1[DD];
    for (int c4 = 0; c4 < DD / 4; ++c4) {
        float4 acc = ((float4*)b1l)[c4];
#pragma unroll
        for (int k = 0; k < DD; ++k) {
            float4 w = ((float4*)W1l)[k * (DD/4) + c4];
            acc.x = fmaf(xr[k], w.x, acc.x);
            acc.y = fmaf(xr[k], w.y, acc.y);
            acc.z = fmaf(xr[k], w.z, acc.z);
            acc.w = fmaf(xr[k], w.w, acc.w);
        }
        z1[c4*4+0] = fmaxf(acc.x, 0.f);
        z1[c4*4+1] = fmaxf(acc.y, 0.f);
        z1[c4*4+2] = fmaxf(acc.z, 0.f);
        z1[c4*4+3] = fmaxf(acc.w, 0.f);
    }
    float4* outrow = (float4*)(out + (size_t)n * DD);
    for (int c4 = 0; c4 < DD / 4; ++c4) {
        float4 acc = ((float4*)b2l)[c4];
#pragma unroll
        for (int k = 0; k < DD; ++k) {
            float4 w = ((float4*)W2l)[k * (DD/4) + c4];
            acc.x = fmaf(z1[k], w.x, acc.x);
            acc.y = fmaf(z1[k], w.y, acc.y);
            acc.z = fmaf(z1[k], w.z, acc.z);
            acc.w = fmaf(z1[k], w.w, acc.w);
        }
        float4 o;
        o.x = fmaxf(acc.x, 0.f); o.y = fmaxf(acc.y, 0.f);
        o.z = fmaxf(acc.z, 0.f); o.w = fmaxf(acc.w, 0.f);
        outrow[c4] = o;
    }
}

// ---------------------------------------------------------------- BN stats
__global__ __launch_bounds__(256) void k_stats(const float* __restrict__ z,
                                               float* __restrict__ stats) {
    int tid = threadIdx.x;
    int c = tid & 63;
    float s = 0.f, s2 = 0.f;
    for (int n = blockIdx.x * 4 + (tid >> 6); n < NN; n += 1024) {
        float v = z[(size_t)n * DD + c];
        s += v;
        s2 = fmaf(v, v, s2);
    }
    __shared__ float red[512];
    red[tid] = s; red[256 + tid] = s2;
    __syncthreads();
    if (tid < 64) {
        float a = red[tid] + red[64+tid] + red[128+tid] + red[192+tid];
        float b = red[256+tid] + red[320+tid] + red[384+tid] + red[448+tid];
        atomicAdd(&stats[c], a);
        atomicAdd(&stats[64 + c], b);
    }
}

__global__ void k_bnfinal(float* __restrict__ stats,
                          const float* __restrict__ gamma,
                          const float* __restrict__ beta) {
    int c = threadIdx.x;  // 64
    float mu  = stats[c] * (1.0f / NN);
    float var = stats[64 + c] * (1.0f / NN) - mu * mu;
    float rstd = rsqrtf(var + 1e-5f);
    float sc = gamma[c] * rstd;
    stats[c] = sc;
    stats[64 + c] = beta[c] - sc * mu;
}

// ------------------------------------------ norm + pool (sorted batch)
__global__ __launch_bounds__(256) void k_norm_pool(
    const float* __restrict__ z, const float* __restrict__ stats,
    const int* __restrict__ batch, float* __restrict__ hout,
    float* __restrict__ pooled, int l)
{
    int wave = (blockIdx.x * 256 + threadIdx.x) >> 6;
    int lane = threadIdx.x & 63;
    int n0 = wave * 64;
    if (n0 >= NN) return;
    int n1 = n0 + 64; if (n1 > NN) n1 = NN;
    float sc = stats[lane], sh = stats[64 + lane];
    int gcur = batch[n0];
    float acc = 0.f;
    for (int n = n0; n < n1; ++n) {
        float h = fmaf(z[(size_t)n * DD + lane], sc, sh);
        hout[(size_t)n * DD + lane] = h;
        int g = batch[n];
        if (g != gcur) {
            atomicAdd(&pooled[(size_t)gcur * (3 * DD) + l * DD + lane], acc);
            gcur = g; acc = 0.f;
        }
        acc += h;
    }
    atomicAdd(&pooled[(size_t)gcur * (3 * DD) + l * DD + lane], acc);
}

// ---------------------------------------------------------------- fallback
__global__ __launch_bounds__(256) void k_copy(const float* __restrict__ src,
                                              float* __restrict__ agg) {
    int total = NN * DD / 4;
    for (int i = blockIdx.x * 256 + threadIdx.x; i < total; i += gridDim.x * 256)
        ((float4*)agg)[i] = ((const float4*)src)[i];
}
__global__ __launch_bounds__(256) void k_edge(
    const float* __restrict__ ea, const float* __restrict__ h,
    const float* __restrict__ W, const float* __restrict__ bias,
    const int* __restrict__ src, const int* __restrict__ dst,
    float* __restrict__ agg)
{
    __shared__ __align__(16) float Wl[DD * DD];
    __shared__ __align__(16) float bl[DD];
    int tid = threadIdx.x;
    for (int i = tid; i < DD * DD / 4; i += 256)
        ((float4*)Wl)[i] = ((const float4*)W)[i];
    if (tid < DD / 4) ((float4*)bl)[tid] = ((const float4*)bias)[tid];
    __syncthreads();
    int e = blockIdx.x * 256 + tid;
    int s = src[e], d = dst[e];
    float av[DD];
    const float4* earow = (const float4*)(ea + (size_t)e * DD);
#pragma unroll
    for (int i = 0; i < DD / 4; ++i) {
        float4 t = earow[i];
        av[4*i] = t.x; av[4*i+1] = t.y; av[4*i+2] = t.z; av[4*i+3] = t.w;
    }
    const float4* hrow = (const float4*)(h + (size_t)s * DD);
    float* arow = agg + (size_t)d * DD;
    for (int c4 = 0; c4 < DD / 4; ++c4) {
        float4 acc = ((float4*)bl)[c4];
#pragma unroll
        for (int k = 0; k < DD; ++k) {
            float4 w = ((float4*)Wl)[k * (DD/4) + c4];
            acc.x = fmaf(av[k], w.x, acc.x);
            acc.y = fmaf(av[k], w.y, acc.y);
            acc.z = fmaf(av[k], w.z, acc.z);
            acc.w = fmaf(av[k], w.w, acc.w);
        }
        float4 hv = hrow[c4];
        atomicAdd(arow + c4*4 + 0, fmaxf(hv.x + acc.x, 0.f));
        atomicAdd(arow + c4*4 + 1, fmaxf(hv.y + acc.y, 0.f));
        atomicAdd(arow + c4*4 + 2, fmaxf(hv.z + acc.z, 0.f));
        atomicAdd(arow + c4*4 + 3, fmaxf(hv.w + acc.w, 0.f));
    }
}

// ----------------------------------------------------------------------------
extern "C" void kernel_launch(void* const* d_in, const int* in_sizes, int n_in,
                              void* d_out, int out_size, void* d_ws, size_t ws_size,
                              hipStream_t stream) {
    const float* x     = (const float*)d_in[0];
    const float* ea    = (const float*)d_in[1];
    const float* We    = (const float*)d_in[2];
    const float* be    = (const float*)d_in[3];
    const float* W1    = (const float*)d_in[4];
    const float* b1    = (const float*)d_in[5];
    const float* W2    = (const float*)d_in[6];
    const float* b2    = (const float*)d_in[7];
    const float* gamma = (const float*)d_in[8];
    const float* beta  = (const float*)d_in[9];
    const int*   eidx  = (const int*)d_in[10];
    const int*   batch = (const int*)d_in[11];
    const int* src = eidx;
    const int* dst = eidx + NE;

    float* out_pool = (float*)d_out;                  // [NG, 3*DD]
    float* out_h    = out_pool + POOLED_F;            // [NN, DD]

    const int exp_sizes[12] = {6400000, 102400000, 12288, 192, 12288, 192,
                               12288, 192, 192, 192, 3200000, 100000};
    bool ok = (n_in == 12);
    for (int i = 0; ok && i < 12; ++i) ok = (in_sizes[i] == exp_sizes[i]);
    if (!ok) {
        k_sentinel<<<1, 64, 0, stream>>>((float*)d_out, 16384.0f);
        return;
    }

    u16*   msgb   = (u16*)d_ws;                            // 3*NE*DD bf16 (614 MB)
    float* agg    = (float*)(msgb + (size_t)3 * NE * DD);  // NN*DD f32
    float* stats  = agg + (size_t)NN * DD;                 // STATS_F
    int*   rowptr = (int*)(stats + STATS_F);               // NN+1
    int*   cursor = rowptr + (NN + 1);                     // NN
    int*   counts = cursor + NN;                           // NN
    int*   epos   = counts + NN;                           // NE
    int*   psrc   = epos + NE;                             // NE
    int*   bsum   = psrc + NE;                             // 256
    int*   boff   = bsum + 256;                            // 256
    size_t needed_fast = (size_t)3 * NE * DD * 2
                       + ((size_t)NN * DD + STATS_F) * 4
                       + ((size_t)(NN + 1) + NN + NN + NE + NE + 512) * 4;

    k_zero<<<(POOLED_F + 255) / 256, 256, 0, stream>>>(out_pool, POOLED_F);

    if (ws_size >= needed_fast) {
        k_zero<<<(STATS_F + 255) / 256, 256, 0, stream>>>(stats, STATS_F);
        k_zeroi<<<(NN + 255) / 256, 256, 0, stream>>>(counts, NN);
        k_hist<<<NE / 256, 256, 0, stream>>>(dst, counts);
        k_scanA<<<SCAN_NB, 512, 0, stream>>>(counts, bsum);
        k_scanB<<<1, 256, 0, stream>>>(bsum, boff, rowptr);
        k_scanC<<<SCAN_NB, 512, 0, stream>>>(counts, boff, rowptr, cursor);
        k_scatter<<<NE / 256, 256, 0, stream>>>(src, dst, cursor, epos, psrc);

        // one fused pass computes all 3 layers' edge GEMMs (bf16 W + bf16 out)
        k_fmsg<<<1024, 256, 0, stream>>>(ea, We, be, epos, msgb);

        for (int l = 0; l < 3; ++l) {
            const float* h = (l == 0) ? x : out_h;
            const u16* msg_l = msgb + (size_t)l * NE * DD;
            k_agg<<<(NN * DD + 255) / 256, 256, 0, stream>>>(msg_l, h, rowptr,
                                                             psrc, agg);
            k_mlp<<<(NN + 255) / 256, 256, 0, stream>>>(agg, W1 + l * DD * DD,
                                                        b1 + l * DD,
                                                        W2 + l * DD * DD,
                                                        b2 + l * DD, agg);
            k_stats<<<256, 256, 0, stream>>>(agg, stats + l * 128);
            k_bnfinal<<<1, 64, 0, stream>>>(stats + l * 128, gamma + l * DD,
                                            beta + l * DD);
            k_norm_pool<<<(NN + 255) / 256, 256, 0, stream>>>(agg, stats + l * 128,
                                                              batch, out_h,
                                                              out_pool, l);
        }
    } else {
        // fallback: round-8 proven f32 path
        float* agg2   = (float*)d_ws;
        float* stats2 = agg2 + (size_t)NN * DD;
        if (ws_size < ((size_t)NN * DD + STATS_F) * sizeof(float)) {
            k_sentinel<<<1, 64, 0, stream>>>((float*)d_out, 32768.0f);
            return;
        }
        k_zero<<<(STATS_F + 255) / 256, 256, 0, stream>>>(stats2, STATS_F);
        for (int l = 0; l < 3; ++l) {
            const float* h = (l == 0) ? x : out_h;
            k_copy<<<2048, 256, 0, stream>>>(h, agg2);
            k_edge<<<NE / 256, 256, 0, stream>>>(ea, h, We + l * DD * DD,
                                                 be + l * DD, src, dst, agg2);
            k_mlp<<<(NN + 255) / 256, 256, 0, stream>>>(agg2, W1 + l * DD * DD,
                                                        b1 + l * DD,
                                                        W2 + l * DD * DD,
                                                        b2 + l * DD, agg2);
            k_stats<<<256, 256, 0, stream>>>(agg2, stats2 + l * 128);
            k_bnfinal<<<1, 64, 0, stream>>>(stats2 + l * 128, gamma + l * DD,
                                            beta + l * DD);
            k_norm_pool<<<(NN + 255) / 256, 256, 0, stream>>>(agg2, stats2 + l * 128,
                                                              batch, out_h,
                                                              out_pool, l);
        }
    }
}